// Round 3
// baseline (8479.077 us; speedup 1.0000x reference)
//
#include <hip/hip_runtime.h>
#include <hip/hip_bf16.h>
#include <cstddef>

typedef __hip_bfloat16 bf16;

static __device__ __forceinline__ float b2f(bf16 v) { return __bfloat162float(v); }
static __device__ __forceinline__ bf16 f2b(float v) { return __float2bfloat16(v); }

// dtype-adaptive parameter load: isbf ? bf16[i] : float[i]
static __device__ __forceinline__ float ldx(const void* p, size_t i, bool isbf) {
    return isbf ? b2f(((const bf16*)p)[i]) : ((const float*)p)[i];
}

#define LN_EPS 1e-5f

// 1-thread dtype probe: `ones` is ffn1_ln_g (all 1.0)
__global__ void detect_kernel(const void* ones, int* flag) {
    unsigned int w = *(const unsigned int*)ones;
    *flag = (w == 0x3F803F80u) ? 1 : 0;
}

__global__ void to_f32_kernel(const void* x, float* __restrict__ y, int n, const int* flag) {
    bool isbf = (*flag != 0);
    int i = blockIdx.x * blockDim.x + threadIdx.x;
    if (i < n) y[i] = ldx(x, i, isbf);
}

// u: (T,1024) bf16 -> o: (T,512) bf16, o = u[:,:512] * sigmoid(u[:,512:])
__global__ void glu_kernel(const bf16* __restrict__ u, bf16* __restrict__ o, int n) {
    int i = blockIdx.x * blockDim.x + threadIdx.x;
    if (i < n) {
        int t = i >> 9, c = i & 511;
        float av = b2f(u[(size_t)t * 1024 + c]);
        float gv = b2f(u[(size_t)t * 1024 + 512 + c]);
        o[i] = f2b(av / (1.f + __expf(-gv)));
    }
}

// LayerNorm over fp32 residual (D=512) -> bf16, one block per token
__global__ __launch_bounds__(256) void ln_kernel(const float* __restrict__ X,
                                                 const void* __restrict__ g,
                                                 const void* __restrict__ b,
                                                 bf16* __restrict__ O, const int* flag) {
    bool isbf = (*flag != 0);
    int t = blockIdx.x, tid = threadIdx.x;
    const float* x = X + (size_t)t * 512;
    float v0 = x[tid], v1 = x[tid + 256];
    __shared__ float rs[256], rq[256];
    rs[tid] = v0 + v1;
    rq[tid] = v0 * v0 + v1 * v1;
    __syncthreads();
    for (int st = 128; st > 0; st >>= 1) {
        if (tid < st) { rs[tid] += rs[tid + st]; rq[tid] += rq[tid + st]; }
        __syncthreads();
    }
    float mean = rs[0] * (1.f / 512.f);
    float var  = rq[0] * (1.f / 512.f) - mean * mean;
    float sc = rsqrtf(var + LN_EPS);
    bf16* o = O + (size_t)t * 512;
    o[tid]       = f2b((v0 - mean) * sc * ldx(g, tid, isbf)       + ldx(b, tid, isbf));
    o[tid + 256] = f2b((v1 - mean) * sc * ldx(g, tid + 256, isbf) + ldx(b, tid + 256, isbf));
}

// final LN: fp32 residual -> output (bf16 or f32 per flag)
__global__ __launch_bounds__(256) void ln_out_kernel(const float* __restrict__ X,
                                                     const void* __restrict__ g,
                                                     const void* __restrict__ b,
                                                     void* __restrict__ O, const int* flag) {
    bool isbf = (*flag != 0);
    int t = blockIdx.x, tid = threadIdx.x;
    const float* x = X + (size_t)t * 512;
    float v0 = x[tid], v1 = x[tid + 256];
    __shared__ float rs[256], rq[256];
    rs[tid] = v0 + v1;
    rq[tid] = v0 * v0 + v1 * v1;
    __syncthreads();
    for (int st = 128; st > 0; st >>= 1) {
        if (tid < st) { rs[tid] += rs[tid + st]; rq[tid] += rq[tid + st]; }
        __syncthreads();
    }
    float mean = rs[0] * (1.f / 512.f);
    float var  = rq[0] * (1.f / 512.f) - mean * mean;
    float sc = rsqrtf(var + LN_EPS);
    float r0 = (v0 - mean) * sc * ldx(g, tid, isbf)       + ldx(b, tid, isbf);
    float r1 = (v1 - mean) * sc * ldx(g, tid + 256, isbf) + ldx(b, tid + 256, isbf);
    size_t off = (size_t)t * 512;
    if (isbf) {
        ((bf16*)O)[off + tid]       = f2b(r0);
        ((bf16*)O)[off + tid + 256] = f2b(r1);
    } else {
        ((float*)O)[off + tid]       = r0;
        ((float*)O)[off + tid + 256] = r1;
    }
}

// GEMM: act(A(rows,K)bf16 @ W(K,M) + bias); W/bias dtype per flag.
// ACT: 0=none, 1=silu. RESADD: 0 -> bf16 Cb; 1 -> res += alpha*v (fp32, M must be 512-row stride of res slice)
template <int ACT, int RESADD>
__global__ __launch_bounds__(256) void gemm_kernel(const bf16* __restrict__ A,
                                                   const void* __restrict__ W,
                                                   const void* __restrict__ bias,
                                                   bf16* __restrict__ Cb,
                                                   float* __restrict__ res, float alpha,
                                                   int K, int M, const int* flag) {
    bool isbf = (*flag != 0);
    __shared__ float As[16][65];
    __shared__ float Bs[16][65];
    int tid = threadIdx.x;
    int tx = tid & 15, ty = tid >> 4;
    int bx = blockIdx.x, by = blockIdx.y;
    int aRow = tid >> 2, aK = (tid & 3) << 2;
    int bK = tid >> 4, bCol = (tid & 15) << 2;
    const bf16* Ab = A + (size_t)(by * 64) * K;
    float acc[4][4] = {};
    for (int kt = 0; kt < K; kt += 16) {
        const bf16* ap = Ab + (size_t)aRow * K + kt + aK;
#pragma unroll
        for (int u = 0; u < 4; ++u) As[aK + u][aRow] = b2f(ap[u]);
        size_t woff = (size_t)(kt + bK) * M + bx * 64 + bCol;
        if (isbf) {
            const bf16* wp = (const bf16*)W + woff;
#pragma unroll
            for (int u = 0; u < 4; ++u) Bs[bK][bCol + u] = b2f(wp[u]);
        } else {
            const float* wp = (const float*)W + woff;
#pragma unroll
            for (int u = 0; u < 4; ++u) Bs[bK][bCol + u] = wp[u];
        }
        __syncthreads();
#pragma unroll
        for (int k = 0; k < 16; ++k) {
            float av[4], bv[4];
#pragma unroll
            for (int i = 0; i < 4; ++i) av[i] = As[k][ty * 4 + i];
#pragma unroll
            for (int j = 0; j < 4; ++j) bv[j] = Bs[k][tx * 4 + j];
#pragma unroll
            for (int i = 0; i < 4; ++i)
#pragma unroll
                for (int j = 0; j < 4; ++j) acc[i][j] += av[i] * bv[j];
        }
        __syncthreads();
    }
#pragma unroll
    for (int j = 0; j < 4; ++j) {
        float bvj = ldx(bias, bx * 64 + tx * 4 + j, isbf);
#pragma unroll
        for (int i = 0; i < 4; ++i) {
            float v = acc[i][j] + bvj;
            if (ACT == 1) v = v / (1.f + __expf(-v));
            size_t off = (size_t)(by * 64 + ty * 4 + i) * M + bx * 64 + tx * 4 + j;
            if (RESADD) res[off] += alpha * v;
            else        Cb[off] = f2b(v);
        }
    }
}

// attention for ONE batch element: Q,K,V (1024,512) bf16; grid (1024 q-pos, 8 heads).
// O may alias Q (each block reads only its own q slice, then writes the same slice).
__global__ __launch_bounds__(256) void attn_kernel(const bf16* __restrict__ Q,
                                                   const bf16* __restrict__ K,
                                                   const bf16* __restrict__ V,
                                                   bf16* __restrict__ O) {
    int s = blockIdx.x, h = blockIdx.y;
    int tid = threadIdx.x;
    __shared__ float q[64];
    __shared__ float sc[1024];
    __shared__ float red[256];
    const bf16* qp = Q + ((size_t)s * 512 + h * 64);
    if (tid < 64) q[tid] = b2f(qp[tid]);
    __syncthreads();
    const bf16* Kb = K + h * 64;
    for (int k = tid; k < 1024; k += 256) {
        const bf16* kp = Kb + (size_t)k * 512;
        float acc = 0.f;
#pragma unroll
        for (int d = 0; d < 64; ++d) acc += q[d] * b2f(kp[d]);
        sc[k] = acc * 0.125f;
    }
    __syncthreads();
    float m = -1e30f;
    for (int k = tid; k < 1024; k += 256) m = fmaxf(m, sc[k]);
    red[tid] = m;
    __syncthreads();
    for (int st = 128; st > 0; st >>= 1) {
        if (tid < st) red[tid] = fmaxf(red[tid], red[tid + st]);
        __syncthreads();
    }
    m = red[0];
    __syncthreads();
    float sum = 0.f;
    for (int k = tid; k < 1024; k += 256) {
        float e = __expf(sc[k] - m);
        sc[k] = e;
        sum += e;
    }
    red[tid] = sum;
    __syncthreads();
    for (int st = 128; st > 0; st >>= 1) {
        if (tid < st) red[tid] += red[tid + st];
        __syncthreads();
    }
    float inv = 1.f / red[0];
    __syncthreads();
    int d = tid & 63, part = tid >> 6;
    const bf16* Vb = V + (h * 64 + d);
    float acc = 0.f;
    int k0 = part * 256;
    for (int k = k0; k < k0 + 256; ++k) acc += sc[k] * b2f(Vb[(size_t)k * 512]);
    red[tid] = acc;
    __syncthreads();
    if (tid < 64) {
        float r = (red[tid] + red[tid + 64]) + (red[tid + 128] + red[tid + 192]);
        O[(size_t)s * 512 + h * 64 + tid] = f2b(r * inv);
    }
}

// depthwise conv (K=31, SAME) + BN + SiLU for ONE batch element: X,Out (1024,512) bf16
__global__ __launch_bounds__(256) void dwconv_kernel(const bf16* __restrict__ X,
                                                     const void* __restrict__ w,
                                                     const void* __restrict__ dwb,
                                                     const void* __restrict__ bng,
                                                     const void* __restrict__ bnb,
                                                     const void* __restrict__ bnm,
                                                     const void* __restrict__ bnv,
                                                     bf16* __restrict__ Out, const int* flag) {
    bool isbf = (*flag != 0);
    int s = blockIdx.x, tid = threadIdx.x;
    for (int c = tid; c < 512; c += 256) {
        float acc = 0.f;
#pragma unroll
        for (int k = 0; k < 31; ++k) {
            int sp = s + k - 15;
            if (sp >= 0 && sp < 1024)
                acc += b2f(X[(size_t)sp * 512 + c]) * ldx(w, c * 31 + k, isbf);
        }
        acc += ldx(dwb, c, isbf);
        float inv = rsqrtf(ldx(bnv, c, isbf) + LN_EPS);
        acc = (acc - ldx(bnm, c, isbf)) * inv * ldx(bng, c, isbf) + ldx(bnb, c, isbf);
        acc = acc / (1.f + __expf(-acc));
        Out[(size_t)s * 512 + c] = f2b(acc);
    }
}

extern "C" void kernel_launch(void* const* d_in, const int* in_sizes, int n_in,
                              void* d_out, int out_size, void* d_ws, size_t ws_size,
                              hipStream_t stream) {
    const int B = 8, S = 1024, D = 512, F = 2048, H = 8;
    const int N = B * S;                // 8192 tokens
    const size_t ND = (size_t)N * D;    // 4,194,304
    if (n_in < 37) return;

    int idx = 0;
    const void* x          = d_in[idx++];
    const void* ffn1_ln_g  = d_in[idx++];
    const void* ffn1_ln_b  = d_in[idx++];
    const void* ffn1_w1    = d_in[idx++];
    const void* ffn1_b1    = d_in[idx++];
    const void* ffn1_w2    = d_in[idx++];
    const void* ffn1_b2    = d_in[idx++];
    const void* mhsa_ln_g  = d_in[idx++];
    const void* mhsa_ln_b  = d_in[idx++];
    const void* wq         = d_in[idx++];
    const void* bq         = d_in[idx++];
    const void* wk         = d_in[idx++];
    const void* bk         = d_in[idx++];
    const void* wv         = d_in[idx++];
    const void* bv         = d_in[idx++];
    const void* wo         = d_in[idx++];
    const void* bo         = d_in[idx++];
    const void* conv_ln_g  = d_in[idx++];
    const void* conv_ln_b  = d_in[idx++];
    const void* pw1_w      = d_in[idx++];
    const void* pw1_b      = d_in[idx++];
    const void* dw_w       = d_in[idx++];
    const void* dw_b       = d_in[idx++];
    const void* bn_g       = d_in[idx++];
    const void* bn_b       = d_in[idx++];
    const void* bn_mean    = d_in[idx++];
    const void* bn_var     = d_in[idx++];
    const void* pw2_w      = d_in[idx++];
    const void* pw2_b      = d_in[idx++];
    const void* ffn2_ln_g  = d_in[idx++];
    const void* ffn2_ln_b  = d_in[idx++];
    const void* ffn2_w1    = d_in[idx++];
    const void* ffn2_b1    = d_in[idx++];
    const void* ffn2_w2    = d_in[idx++];
    const void* ffn2_b2    = d_in[idx++];
    const void* final_ln_g = d_in[idx++];
    const void* final_ln_b = d_in[idx++];

    // ws layout: [0,256) flag | [256, 256+16MB) res fp32 | [+8MB) big scratch  => ~24.3 MB
    char* wsb  = (char*)d_ws;
    int*  flag = (int*)wsb;
    float* res = (float*)(wsb + 256);
    char*  big = wsb + 256 + ND * 4;
    bf16*  h   = (bf16*)d_out;          // LN output lives in d_out until the final store

    detect_kernel<<<1, 1, 0, stream>>>(ffn1_ln_g, flag);
    to_f32_kernel<<<(int)(ND / 256), 256, 0, stream>>>(x, res, (int)ND, flag);

    auto run_ffn = [&](const void* lg, const void* lb, const void* w1, const void* b1,
                       const void* w2, const void* b2) {
        ln_kernel<<<N, 256, 0, stream>>>(res, lg, lb, h, flag);
        for (int c = 0; c < 4; ++c) {                       // 2048-token chunks
            const bf16* Ah = h + (size_t)c * 2048 * D;
            bf16* mid = (bf16*)big;                         // 2048 x 2048 bf16 = 8 MB
            gemm_kernel<1, 0><<<dim3(F / 64, 2048 / 64), 256, 0, stream>>>(
                Ah, w1, b1, mid, nullptr, 0.f, D, F, flag);
            gemm_kernel<0, 1><<<dim3(D / 64, 2048 / 64), 256, 0, stream>>>(
                mid, w2, b2, nullptr, res + (size_t)c * 2048 * D, 0.5f, F, D, flag);
        }
    };

    // ---- FFN1 ----
    run_ffn(ffn1_ln_g, ffn1_ln_b, ffn1_w1, ffn1_b1, ffn1_w2, ffn1_b2);

    // ---- MHSA (per batch element) ----
    {
        ln_kernel<<<N, 256, 0, stream>>>(res, mhsa_ln_g, mhsa_ln_b, h, flag);
        for (int b = 0; b < B; ++b) {
            bf16* Q  = (bf16*)big;                          // 1 MB each
            bf16* Kb = Q + (size_t)S * D;
            bf16* V  = Kb + (size_t)S * D;
            const bf16* Ah = h + (size_t)b * S * D;
            gemm_kernel<0, 0><<<dim3(D / 64, S / 64), 256, 0, stream>>>(Ah, wq, bq, Q,  nullptr, 0.f, D, D, flag);
            gemm_kernel<0, 0><<<dim3(D / 64, S / 64), 256, 0, stream>>>(Ah, wk, bk, Kb, nullptr, 0.f, D, D, flag);
            gemm_kernel<0, 0><<<dim3(D / 64, S / 64), 256, 0, stream>>>(Ah, wv, bv, V,  nullptr, 0.f, D, D, flag);
            attn_kernel<<<dim3(S, H), 256, 0, stream>>>(Q, Kb, V, Q);   // in-place Q -> ctx
            gemm_kernel<0, 1><<<dim3(D / 64, S / 64), 256, 0, stream>>>(
                Q, wo, bo, nullptr, res + (size_t)b * S * D, 1.0f, D, D, flag);
        }
    }

    // ---- Conv module (per batch element) ----
    {
        ln_kernel<<<N, 256, 0, stream>>>(res, conv_ln_g, conv_ln_b, h, flag);
        for (int b = 0; b < B; ++b) {
            bf16* u  = (bf16*)big;                          // 1024 x 1024 = 2 MB
            bf16* hg = (bf16*)(big + (size_t)S * 2 * D * 2);// 1 MB
            bf16* dw = hg + (size_t)S * D;                  // 1 MB
            const bf16* Ah = h + (size_t)b * S * D;
            gemm_kernel<0, 0><<<dim3((2 * D) / 64, S / 64), 256, 0, stream>>>(
                Ah, pw1_w, pw1_b, u, nullptr, 0.f, D, 2 * D, flag);
            glu_kernel<<<(S * D) / 256, 256, 0, stream>>>(u, hg, S * D);
            dwconv_kernel<<<S, 256, 0, stream>>>(hg, dw_w, dw_b, bn_g, bn_b, bn_mean, bn_var, dw, flag);
            gemm_kernel<0, 1><<<dim3(D / 64, S / 64), 256, 0, stream>>>(
                dw, pw2_w, pw2_b, nullptr, res + (size_t)b * S * D, 1.0f, D, D, flag);
        }
    }

    // ---- FFN2 ----
    run_ffn(ffn2_ln_g, ffn2_ln_b, ffn2_w1, ffn2_b1, ffn2_w2, ffn2_b2);

    // ---- final LN -> d_out ----
    ln_out_kernel<<<N, 256, 0, stream>>>(res, final_ln_g, final_ln_b, d_out, flag);
}

// Round 4
// 3484.813 us; speedup vs baseline: 2.4332x; 2.4332x over previous
//
#include <hip/hip_runtime.h>
#include <hip/hip_bf16.h>
#include <cstddef>

typedef __hip_bfloat16 bf16;
typedef __attribute__((ext_vector_type(8))) short bf16x8;
typedef __attribute__((ext_vector_type(4))) float f32x4;

static __device__ __forceinline__ float b2f(bf16 v) { return __bfloat162float(v); }
static __device__ __forceinline__ bf16 f2b(float v) { return __float2bfloat16(v); }
static __device__ __forceinline__ float bits2f(unsigned short u) {
    union { unsigned int i; float f; } c; c.i = ((unsigned int)u) << 16; return c.f;
}
static __device__ __forceinline__ float ldx(const void* p, size_t i, bool isbf) {
    return isbf ? b2f(((const bf16*)p)[i]) : ((const float*)p)[i];
}

#define LN_EPS 1e-5f

// ---------------- dtype probe ----------------
__global__ void detect_kernel(const void* ones, int* flag) {
    unsigned int w = *(const unsigned int*)ones;
    *flag = (w == 0x3F803F80u) ? 1 : 0;
}

__global__ void to_f32_kernel(const void* x, float* __restrict__ y, int n, const int* flag) {
    bool isbf = (*flag != 0);
    int i = blockIdx.x * blockDim.x + threadIdx.x;
    if (i < n) y[i] = ldx(x, i, isbf);
}

// ---------------- weight transpose: W (K x M, dtype flag) -> Wt (M x K, bf16) ----------------
__global__ __launch_bounds__(256) void transpose_kernel(const void* __restrict__ W,
                                                        bf16* __restrict__ Wt,
                                                        int K, int M, const int* flag) {
    bool isbf = (*flag != 0);
    __shared__ float ts[32][33];
    int kt0 = blockIdx.x * 32, mt0 = blockIdx.y * 32;
    int x = threadIdx.x, y = threadIdx.y;  // block (32,8)
    for (int yy = y; yy < 32; yy += 8)
        ts[yy][x] = ldx(W, (size_t)(kt0 + yy) * M + mt0 + x, isbf);
    __syncthreads();
    for (int yy = y; yy < 32; yy += 8)
        Wt[(size_t)(mt0 + yy) * K + kt0 + x] = f2b(ts[x][yy]);
}

// ---------------- GLU: u (T,1024) -> o (T,512) ----------------
__global__ void glu_kernel(const bf16* __restrict__ u, bf16* __restrict__ o, int n) {
    int i = blockIdx.x * blockDim.x + threadIdx.x;
    if (i < n) {
        int t = i >> 9, c = i & 511;
        float av = b2f(u[(size_t)t * 1024 + c]);
        float gv = b2f(u[(size_t)t * 1024 + 512 + c]);
        o[i] = f2b(av / (1.f + __expf(-gv)));
    }
}

// ---------------- LayerNorm: fp32 residual -> bf16 ----------------
__global__ __launch_bounds__(256) void ln_kernel(const float* __restrict__ X,
                                                 const void* __restrict__ g,
                                                 const void* __restrict__ b,
                                                 bf16* __restrict__ O, const int* flag) {
    bool isbf = (*flag != 0);
    int t = blockIdx.x, tid = threadIdx.x;
    const float* x = X + (size_t)t * 512;
    float v0 = x[tid], v1 = x[tid + 256];
    __shared__ float rs[256], rq[256];
    rs[tid] = v0 + v1;
    rq[tid] = v0 * v0 + v1 * v1;
    __syncthreads();
    for (int st = 128; st > 0; st >>= 1) {
        if (tid < st) { rs[tid] += rs[tid + st]; rq[tid] += rq[tid + st]; }
        __syncthreads();
    }
    float mean = rs[0] * (1.f / 512.f);
    float var  = rq[0] * (1.f / 512.f) - mean * mean;
    float sc = rsqrtf(var + LN_EPS);
    bf16* o = O + (size_t)t * 512;
    o[tid]       = f2b((v0 - mean) * sc * ldx(g, tid, isbf)       + ldx(b, tid, isbf));
    o[tid + 256] = f2b((v1 - mean) * sc * ldx(g, tid + 256, isbf) + ldx(b, tid + 256, isbf));
}

__global__ __launch_bounds__(256) void ln_out_kernel(const float* __restrict__ X,
                                                     const void* __restrict__ g,
                                                     const void* __restrict__ b,
                                                     void* __restrict__ O, const int* flag) {
    bool isbf = (*flag != 0);
    int t = blockIdx.x, tid = threadIdx.x;
    const float* x = X + (size_t)t * 512;
    float v0 = x[tid], v1 = x[tid + 256];
    __shared__ float rs[256], rq[256];
    rs[tid] = v0 + v1;
    rq[tid] = v0 * v0 + v1 * v1;
    __syncthreads();
    for (int st = 128; st > 0; st >>= 1) {
        if (tid < st) { rs[tid] += rs[tid + st]; rq[tid] += rq[tid + st]; }
        __syncthreads();
    }
    float mean = rs[0] * (1.f / 512.f);
    float var  = rq[0] * (1.f / 512.f) - mean * mean;
    float sc = rsqrtf(var + LN_EPS);
    float r0 = (v0 - mean) * sc * ldx(g, tid, isbf)       + ldx(b, tid, isbf);
    float r1 = (v1 - mean) * sc * ldx(g, tid + 256, isbf) + ldx(b, tid + 256, isbf);
    size_t off = (size_t)t * 512;
    if (isbf) {
        ((bf16*)O)[off + tid]       = f2b(r0);
        ((bf16*)O)[off + tid + 256] = f2b(r1);
    } else {
        ((float*)O)[off + tid]       = r0;
        ((float*)O)[off + tid + 256] = r1;
    }
}

// ---------------- MFMA GEMM: C(rows,M) = act(A(rows,K) @ Wt(M,K)^T + bias) ----------------
// 128x128 tile / block, 4 waves in 2x2, each wave 64x64 via 4x4 mfma_16x16x32 accs, BK=32.
// ACT: 0=none, 1=silu. RESADD: 1 -> res[row*512+col] += alpha*v (requires M==512).
template <int ACT, int RESADD>
__global__ __launch_bounds__(256) void mgemm_kernel(const bf16* __restrict__ A,
                                                    const bf16* __restrict__ Wt,
                                                    const void* __restrict__ bias,
                                                    bf16* __restrict__ Cb,
                                                    float* __restrict__ res, float alpha,
                                                    int K, int M, const int* flag) {
    bool isbf = (*flag != 0);
    __shared__ short As[128][40];   // [row][k], +8 pad
    __shared__ short Bs[128][40];   // [col][k], +8 pad
    int tid = threadIdx.x;
    int rowBase = blockIdx.y * 128, colBase = blockIdx.x * 128;
    int ll = tid & 63, wv = tid >> 6;
    int wr = (wv & 1) * 64, wc = (wv >> 1) * 64;
    int lRow = ll & 15, quad = ll >> 4;
    int sR = tid >> 2, sKg = (tid & 3) * 8;   // staging: 2 slots/thread (rows sR, sR+64)

    f32x4 acc[4][4] = {};

    for (int k0 = 0; k0 < K; k0 += 32) {
        const bf16* ap0 = A  + (size_t)(rowBase + sR) * K + k0 + sKg;
        const bf16* ap1 = A  + (size_t)(rowBase + 64 + sR) * K + k0 + sKg;
        const bf16* bp0 = Wt + (size_t)(colBase + sR) * K + k0 + sKg;
        const bf16* bp1 = Wt + (size_t)(colBase + 64 + sR) * K + k0 + sKg;
        *(bf16x8*)&As[sR][sKg]      = *(const bf16x8*)ap0;
        *(bf16x8*)&As[sR + 64][sKg] = *(const bf16x8*)ap1;
        *(bf16x8*)&Bs[sR][sKg]      = *(const bf16x8*)bp0;
        *(bf16x8*)&Bs[sR + 64][sKg] = *(const bf16x8*)bp1;
        __syncthreads();
        bf16x8 af[4], bfv[4];
#pragma unroll
        for (int i = 0; i < 4; ++i) af[i]  = *(const bf16x8*)&As[wr + i * 16 + lRow][quad * 8];
#pragma unroll
        for (int j = 0; j < 4; ++j) bfv[j] = *(const bf16x8*)&Bs[wc + j * 16 + lRow][quad * 8];
#pragma unroll
        for (int i = 0; i < 4; ++i)
#pragma unroll
            for (int j = 0; j < 4; ++j)
                acc[i][j] = __builtin_amdgcn_mfma_f32_16x16x32_bf16(af[i], bfv[j], acc[i][j], 0, 0, 0);
        __syncthreads();
    }

#pragma unroll
    for (int j = 0; j < 4; ++j) {
        int col = colBase + wc + j * 16 + lRow;
        float bv = ldx(bias, col, isbf);
#pragma unroll
        for (int i = 0; i < 4; ++i) {
            int r0 = rowBase + wr + i * 16 + quad * 4;
#pragma unroll
            for (int r = 0; r < 4; ++r) {
                float v = acc[i][j][r] + bv;
                if (ACT == 1) v = v / (1.f + __expf(-v));
                int row = r0 + r;
                if (RESADD) res[(size_t)row * 512 + col] += alpha * v;
                else        Cb[(size_t)row * M + col] = f2b(v);
            }
        }
    }
}

// ---------------- attention (vectorized): slab of nb batches, Q/K/V (nb,1024,512) ----------------
// grid (1024, 8, nb). O aliases Q safely (block reads only its own q row).
__global__ __launch_bounds__(256) void attn_kernel(const bf16* __restrict__ Q,
                                                   const bf16* __restrict__ K,
                                                   const bf16* __restrict__ V,
                                                   bf16* __restrict__ O) {
    int s = blockIdx.x, h = blockIdx.y, b = blockIdx.z;
    int tid = threadIdx.x;
    __shared__ float q[64];
    __shared__ float sc[1024];
    __shared__ float red[256];
    __shared__ float red2[256][8];
    size_t bOff = (size_t)b * 1024 * 512;
    const bf16* qp = Q + bOff + (size_t)s * 512 + h * 64;
    if (tid < 64) q[tid] = b2f(qp[tid]);
    __syncthreads();
    // QK^T: 4 keys per thread, 16B vector loads
    const bf16* Kb = K + bOff + h * 64;
    for (int k = tid; k < 1024; k += 256) {
        const bf16* kp = Kb + (size_t)k * 512;
        float acc = 0.f;
#pragma unroll
        for (int g8 = 0; g8 < 8; ++g8) {
            bf16x8 kv = *(const bf16x8*)(kp + g8 * 8);
#pragma unroll
            for (int u = 0; u < 8; ++u)
                acc += q[g8 * 8 + u] * bits2f((unsigned short)kv[u]);
        }
        sc[k] = acc * 0.125f;
    }
    __syncthreads();
    float m = -1e30f;
    for (int k = tid; k < 1024; k += 256) m = fmaxf(m, sc[k]);
    red[tid] = m;
    __syncthreads();
    for (int st = 128; st > 0; st >>= 1) {
        if (tid < st) red[tid] = fmaxf(red[tid], red[tid + st]);
        __syncthreads();
    }
    m = red[0];
    __syncthreads();
    float sum = 0.f;
    for (int k = tid; k < 1024; k += 256) {
        float e = __expf(sc[k] - m);
        sc[k] = e;
        sum += e;
    }
    red[tid] = sum;
    __syncthreads();
    for (int st = 128; st > 0; st >>= 1) {
        if (tid < st) red[tid] += red[tid + st];
        __syncthreads();
    }
    float inv = 1.f / red[0];
    __syncthreads();
    // PV: thread t -> dgroup = t&7 (8 dims), kpart = t>>3 (32 k's each)
    int dg = tid & 7, kp0 = (tid >> 3) * 32;
    const bf16* Vb = V + bOff + h * 64 + dg * 8;
    float a8[8] = {};
    for (int k = kp0; k < kp0 + 32; ++k) {
        bf16x8 vv = *(const bf16x8*)(Vb + (size_t)k * 512);
        float p = sc[k];
#pragma unroll
        for (int u = 0; u < 8; ++u) a8[u] += p * bits2f((unsigned short)vv[u]);
    }
#pragma unroll
    for (int u = 0; u < 8; ++u) red2[tid][u] = a8[u];
    __syncthreads();
    if (tid < 64) {
        int dgx = tid >> 3, ux = tid & 7;
        float r = 0.f;
#pragma unroll
        for (int kp = 0; kp < 32; ++kp) r += red2[kp * 8 + dgx][ux];
        O[bOff + (size_t)s * 512 + h * 64 + tid] = f2b(r * inv);
    }
}

// ---------------- depthwise conv + BN + SiLU: slab (nb,1024,512), grid (1024, nb) ----------------
__global__ __launch_bounds__(256) void dwconv_kernel(const bf16* __restrict__ X,
                                                     const void* __restrict__ w,
                                                     const void* __restrict__ dwb,
                                                     const void* __restrict__ bng,
                                                     const void* __restrict__ bnb,
                                                     const void* __restrict__ bnm,
                                                     const void* __restrict__ bnv,
                                                     bf16* __restrict__ Out, const int* flag) {
    bool isbf = (*flag != 0);
    int s = blockIdx.x, tid = threadIdx.x;
    size_t bOff = (size_t)blockIdx.y * 1024 * 512;
    int c0 = tid * 2;
    float a0 = 0.f, a1 = 0.f;
#pragma unroll
    for (int k = 0; k < 31; ++k) {
        int sp = s + k - 15;
        if (sp >= 0 && sp < 1024) {
            const bf16* xp = X + bOff + (size_t)sp * 512 + c0;
            a0 += b2f(xp[0]) * ldx(w, (size_t)c0 * 31 + k, isbf);
            a1 += b2f(xp[1]) * ldx(w, (size_t)(c0 + 1) * 31 + k, isbf);
        }
    }
    float o[2] = {a0, a1};
#pragma unroll
    for (int u = 0; u < 2; ++u) {
        int c = c0 + u;
        float v = o[u] + ldx(dwb, c, isbf);
        float iv = rsqrtf(ldx(bnv, c, isbf) + LN_EPS);
        v = (v - ldx(bnm, c, isbf)) * iv * ldx(bng, c, isbf) + ldx(bnb, c, isbf);
        v = v / (1.f + __expf(-v));
        Out[bOff + (size_t)s * 512 + c] = f2b(v);
    }
}

extern "C" void kernel_launch(void* const* d_in, const int* in_sizes, int n_in,
                              void* d_out, int out_size, void* d_ws, size_t ws_size,
                              hipStream_t stream) {
    const int B = 8, S = 1024, D = 512, F = 2048, H = 8;
    const int N = B * S;
    const size_t ND = (size_t)N * D;
    if (n_in < 37) return;

    int idx = 0;
    const void* x          = d_in[idx++];
    const void* ffn1_ln_g  = d_in[idx++];
    const void* ffn1_ln_b  = d_in[idx++];
    const void* ffn1_w1    = d_in[idx++];
    const void* ffn1_b1    = d_in[idx++];
    const void* ffn1_w2    = d_in[idx++];
    const void* ffn1_b2    = d_in[idx++];
    const void* mhsa_ln_g  = d_in[idx++];
    const void* mhsa_ln_b  = d_in[idx++];
    const void* wq         = d_in[idx++];
    const void* bq         = d_in[idx++];
    const void* wk         = d_in[idx++];
    const void* bk         = d_in[idx++];
    const void* wv         = d_in[idx++];
    const void* bv         = d_in[idx++];
    const void* wo         = d_in[idx++];
    const void* bo         = d_in[idx++];
    const void* conv_ln_g  = d_in[idx++];
    const void* conv_ln_b  = d_in[idx++];
    const void* pw1_w      = d_in[idx++];
    const void* pw1_b      = d_in[idx++];
    const void* dw_w       = d_in[idx++];
    const void* dw_b       = d_in[idx++];
    const void* bn_g       = d_in[idx++];
    const void* bn_b       = d_in[idx++];
    const void* bn_mean    = d_in[idx++];
    const void* bn_var     = d_in[idx++];
    const void* pw2_w      = d_in[idx++];
    const void* pw2_b      = d_in[idx++];
    const void* ffn2_ln_g  = d_in[idx++];
    const void* ffn2_ln_b  = d_in[idx++];
    const void* ffn2_w1    = d_in[idx++];
    const void* ffn2_b1    = d_in[idx++];
    const void* ffn2_w2    = d_in[idx++];
    const void* ffn2_b2    = d_in[idx++];
    const void* final_ln_g = d_in[idx++];
    const void* final_ln_b = d_in[idx++];

    // ws layout: [0,1KB) flag | res fp32 16MB | Wt 4MB | scratch (rest, sized by ws_size)
    const size_t MB = 1024 * 1024;
    char* wsb  = (char*)d_ws;
    int*  flag = (int*)wsb;
    float* res = (float*)(wsb + 1024);
    bf16*  wt  = (bf16*)(wsb + 1024 + ND * 4);
    char*  scr = wsb + 1024 + ND * 4 + 4 * MB;
    size_t scrB = (ws_size > 1024 + ND * 4 + 4 * MB) ? ws_size - (1024 + ND * 4 + 4 * MB) : 0;
    // fallback floor (known-good 24 MB total): scratch >= 4 MB assumed available
    int ffnRows = (scrB >= 8 * MB) ? 2048 : 1024;        // mid = ffnRows*2048*2 bytes
    int bI      = (scrB >= 6 * MB) ? 2 : 1;              // MHSA batches per iter (3*bI MB)
    int cI      = (scrB >= 8 * MB) ? 2 : 1;              // conv batches per iter (4*cI MB)

    bf16* h = (bf16*)d_out;   // LN output parked in d_out (overwritten by final LN)

    detect_kernel<<<1, 1, 0, stream>>>(ffn1_ln_g, flag);
    to_f32_kernel<<<(int)(ND / 256), 256, 0, stream>>>(x, res, (int)ND, flag);

    auto run_ffn = [&](const void* lg, const void* lb, const void* w1, const void* b1,
                       const void* w2, const void* b2) {
        bf16* w1t = wt;                       // (2048,512)  2 MB
        bf16* w2t = wt + (size_t)D * F;       // (512,2048)  2 MB
        transpose_kernel<<<dim3(D / 32, F / 32), dim3(32, 8), 0, stream>>>(w1, w1t, D, F, flag);
        transpose_kernel<<<dim3(F / 32, D / 32), dim3(32, 8), 0, stream>>>(w2, w2t, F, D, flag);
        ln_kernel<<<N, 256, 0, stream>>>(res, lg, lb, h, flag);
        bf16* mid = (bf16*)scr;
        for (int r0 = 0; r0 < N; r0 += ffnRows) {
            mgemm_kernel<1, 0><<<dim3(F / 128, ffnRows / 128), 256, 0, stream>>>(
                h + (size_t)r0 * D, w1t, b1, mid, nullptr, 0.f, D, F, flag);
            mgemm_kernel<0, 1><<<dim3(D / 128, ffnRows / 128), 256, 0, stream>>>(
                mid, w2t, b2, nullptr, res + (size_t)r0 * D, 0.5f, F, D, flag);
        }
    };

    // ---- FFN1 ----
    run_ffn(ffn1_ln_g, ffn1_ln_b, ffn1_w1, ffn1_b1, ffn1_w2, ffn1_b2);

    // ---- MHSA ----
    {
        bf16* qt = wt;
        bf16* kt = wt + (size_t)D * D;
        bf16* vt = wt + 2 * (size_t)D * D;
        bf16* ot = wt + 3 * (size_t)D * D;
        transpose_kernel<<<dim3(D / 32, D / 32), dim3(32, 8), 0, stream>>>(wq, qt, D, D, flag);
        transpose_kernel<<<dim3(D / 32, D / 32), dim3(32, 8), 0, stream>>>(wk, kt, D, D, flag);
        transpose_kernel<<<dim3(D / 32, D / 32), dim3(32, 8), 0, stream>>>(wv, vt, D, D, flag);
        transpose_kernel<<<dim3(D / 32, D / 32), dim3(32, 8), 0, stream>>>(wo, ot, D, D, flag);
        ln_kernel<<<N, 256, 0, stream>>>(res, mhsa_ln_g, mhsa_ln_b, h, flag);
        for (int b = 0; b < B; b += bI) {
            int rows = bI * S;
            bf16* Q  = (bf16*)scr;
            bf16* Kb = Q + (size_t)rows * D;
            bf16* V  = Kb + (size_t)rows * D;
            const bf16* Ah = h + (size_t)b * S * D;
            mgemm_kernel<0, 0><<<dim3(D / 128, rows / 128), 256, 0, stream>>>(Ah, qt, bq, Q,  nullptr, 0.f, D, D, flag);
            mgemm_kernel<0, 0><<<dim3(D / 128, rows / 128), 256, 0, stream>>>(Ah, kt, bk, Kb, nullptr, 0.f, D, D, flag);
            mgemm_kernel<0, 0><<<dim3(D / 128, rows / 128), 256, 0, stream>>>(Ah, vt, bv, V,  nullptr, 0.f, D, D, flag);
            attn_kernel<<<dim3(S, H, bI), 256, 0, stream>>>(Q, Kb, V, Q);  // in-place ctx
            mgemm_kernel<0, 1><<<dim3(D / 128, rows / 128), 256, 0, stream>>>(
                Q, ot, bo, nullptr, res + (size_t)b * S * D, 1.0f, D, D, flag);
        }
    }

    // ---- Conv module ----
    {
        bf16* p1t = wt;                         // (1024,512) 1 MB
        bf16* p2t = wt + (size_t)D * 2 * D;     // (512,512) 0.5 MB
        transpose_kernel<<<dim3(D / 32, (2 * D) / 32), dim3(32, 8), 0, stream>>>(pw1_w, p1t, D, 2 * D, flag);
        transpose_kernel<<<dim3(D / 32, D / 32), dim3(32, 8), 0, stream>>>(pw2_w, p2t, D, D, flag);
        ln_kernel<<<N, 256, 0, stream>>>(res, conv_ln_g, conv_ln_b, h, flag);
        for (int b = 0; b < B; b += cI) {
            int rows = cI * S;
            bf16* u  = (bf16*)scr;                         // rows x 1024
            bf16* hg = u + (size_t)rows * 2 * D;           // rows x 512
            bf16* dw = hg + (size_t)rows * D;              // rows x 512
            const bf16* Ah = h + (size_t)b * S * D;
            mgemm_kernel<0, 0><<<dim3((2 * D) / 128, rows / 128), 256, 0, stream>>>(
                Ah, p1t, pw1_b, u, nullptr, 0.f, D, 2 * D, flag);
            glu_kernel<<<(rows * D) / 256, 256, 0, stream>>>(u, hg, rows * D);
            dwconv_kernel<<<dim3(S, cI), 256, 0, stream>>>(hg, dw_w, dw_b, bn_g, bn_b, bn_mean, bn_var, dw, flag);
            mgemm_kernel<0, 1><<<dim3(D / 128, rows / 128), 256, 0, stream>>>(
                dw, p2t, pw2_b, nullptr, res + (size_t)b * S * D, 1.0f, D, D, flag);
        }
    }

    // ---- FFN2 ----
    run_ffn(ffn2_ln_g, ffn2_ln_b, ffn2_w1, ffn2_b1, ffn2_w2, ffn2_b2);

    // ---- final LN -> d_out ----
    ln_out_kernel<<<N, 256, 0, stream>>>(res, final_ln_g, final_ln_b, d_out, flag);
}

// Round 5
// 1096.138 us; speedup vs baseline: 7.7354x; 3.1792x over previous
//
#include <hip/hip_runtime.h>
#include <hip/hip_bf16.h>
#include <cstddef>

typedef __hip_bfloat16 bf16;
typedef __attribute__((ext_vector_type(8))) short bf16x8;
typedef __attribute__((ext_vector_type(4))) float f32x4;

static __device__ __forceinline__ float b2f(bf16 v) { return __bfloat162float(v); }
static __device__ __forceinline__ bf16 f2b(float v) { return __float2bfloat16(v); }
static __device__ __forceinline__ float ldx(const void* p, size_t i, bool isbf) {
    return isbf ? b2f(((const bf16*)p)[i]) : ((const float*)p)[i];
}

#define LN_EPS 1e-5f

// ---------------- dtype probe ----------------
__global__ void detect_kernel(const void* ones, int* flag) {
    unsigned int w = *(const unsigned int*)ones;
    *flag = (w == 0x3F803F80u) ? 1 : 0;
}

__global__ void to_f32_kernel(const void* x, float* __restrict__ y, int n, const int* flag) {
    bool isbf = (*flag != 0);
    int i = blockIdx.x * blockDim.x + threadIdx.x;
    if (i < n) y[i] = ldx(x, i, isbf);
}

// ---------------- weight transpose: W (K x M) -> Wt (M x K) bf16 ----------------
__global__ __launch_bounds__(256) void transpose_kernel(const void* __restrict__ W,
                                                        bf16* __restrict__ Wt,
                                                        int K, int M, const int* flag) {
    bool isbf = (*flag != 0);
    __shared__ float ts[32][33];
    int kt0 = blockIdx.x * 32, mt0 = blockIdx.y * 32;
    int x = threadIdx.x, y = threadIdx.y;  // block (32,8)
    for (int yy = y; yy < 32; yy += 8)
        ts[yy][x] = ldx(W, (size_t)(kt0 + yy) * M + mt0 + x, isbf);
    __syncthreads();
    for (int yy = y; yy < 32; yy += 8)
        Wt[(size_t)(mt0 + yy) * K + kt0 + x] = f2b(ts[x][yy]);
}

// ---------------- V transpose per batch: V (nb,1024,512) -> Vt (nb,512,1024) ----------------
__global__ __launch_bounds__(256) void vtrans_kernel(const bf16* __restrict__ V,
                                                     bf16* __restrict__ Vt) {
    __shared__ bf16 t[32][33];
    int s0 = blockIdx.x * 32, c0 = blockIdx.y * 32, b = blockIdx.z;
    int x = threadIdx.x, y = threadIdx.y;  // block (32,8)
    const bf16* Vb = V + (size_t)b * 1024 * 512;
    bf16* Vtb = Vt + (size_t)b * 512 * 1024;
    for (int yy = y; yy < 32; yy += 8)
        t[yy][x] = Vb[(size_t)(s0 + yy) * 512 + c0 + x];
    __syncthreads();
    for (int yy = y; yy < 32; yy += 8)
        Vtb[(size_t)(c0 + yy) * 1024 + s0 + x] = t[x][yy];
}

// ---------------- GLU ----------------
__global__ void glu_kernel(const bf16* __restrict__ u, bf16* __restrict__ o, int n) {
    int i = blockIdx.x * blockDim.x + threadIdx.x;
    if (i < n) {
        int t = i >> 9, c = i & 511;
        float av = b2f(u[(size_t)t * 1024 + c]);
        float gv = b2f(u[(size_t)t * 1024 + 512 + c]);
        o[i] = f2b(av / (1.f + __expf(-gv)));
    }
}

// ---------------- LayerNorm ----------------
__global__ __launch_bounds__(256) void ln_kernel(const float* __restrict__ X,
                                                 const void* __restrict__ g,
                                                 const void* __restrict__ b,
                                                 bf16* __restrict__ O, const int* flag) {
    bool isbf = (*flag != 0);
    int t = blockIdx.x, tid = threadIdx.x;
    const float* x = X + (size_t)t * 512;
    float v0 = x[tid], v1 = x[tid + 256];
    __shared__ float rs[256], rq[256];
    rs[tid] = v0 + v1;
    rq[tid] = v0 * v0 + v1 * v1;
    __syncthreads();
    for (int st = 128; st > 0; st >>= 1) {
        if (tid < st) { rs[tid] += rs[tid + st]; rq[tid] += rq[tid + st]; }
        __syncthreads();
    }
    float mean = rs[0] * (1.f / 512.f);
    float var  = rq[0] * (1.f / 512.f) - mean * mean;
    float sc = rsqrtf(var + LN_EPS);
    bf16* o = O + (size_t)t * 512;
    o[tid]       = f2b((v0 - mean) * sc * ldx(g, tid, isbf)       + ldx(b, tid, isbf));
    o[tid + 256] = f2b((v1 - mean) * sc * ldx(g, tid + 256, isbf) + ldx(b, tid + 256, isbf));
}

__global__ __launch_bounds__(256) void ln_out_kernel(const float* __restrict__ X,
                                                     const void* __restrict__ g,
                                                     const void* __restrict__ b,
                                                     void* __restrict__ O, const int* flag) {
    bool isbf = (*flag != 0);
    int t = blockIdx.x, tid = threadIdx.x;
    const float* x = X + (size_t)t * 512;
    float v0 = x[tid], v1 = x[tid + 256];
    __shared__ float rs[256], rq[256];
    rs[tid] = v0 + v1;
    rq[tid] = v0 * v0 + v1 * v1;
    __syncthreads();
    for (int st = 128; st > 0; st >>= 1) {
        if (tid < st) { rs[tid] += rs[tid + st]; rq[tid] += rq[tid + st]; }
        __syncthreads();
    }
    float mean = rs[0] * (1.f / 512.f);
    float var  = rq[0] * (1.f / 512.f) - mean * mean;
    float sc = rsqrtf(var + LN_EPS);
    float r0 = (v0 - mean) * sc * ldx(g, tid, isbf)       + ldx(b, tid, isbf);
    float r1 = (v1 - mean) * sc * ldx(g, tid + 256, isbf) + ldx(b, tid + 256, isbf);
    size_t off = (size_t)t * 512;
    if (isbf) {
        ((bf16*)O)[off + tid]       = f2b(r0);
        ((bf16*)O)[off + tid + 256] = f2b(r1);
    } else {
        ((float*)O)[off + tid]       = r0;
        ((float*)O)[off + tid + 256] = r1;
    }
}

// ---------------- MFMA GEMM (128x128 tile, BK=32) ----------------
template <int ACT, int RESADD>
__global__ __launch_bounds__(256) void mgemm_kernel(const bf16* __restrict__ A,
                                                    const bf16* __restrict__ Wt,
                                                    const void* __restrict__ bias,
                                                    bf16* __restrict__ Cb,
                                                    float* __restrict__ res, float alpha,
                                                    int K, int M, const int* flag) {
    bool isbf = (*flag != 0);
    __shared__ short As[128][40];
    __shared__ short Bs[128][40];
    int tid = threadIdx.x;
    int rowBase = blockIdx.y * 128, colBase = blockIdx.x * 128;
    int ll = tid & 63, wv = tid >> 6;
    int wr = (wv & 1) * 64, wc = (wv >> 1) * 64;
    int lRow = ll & 15, quad = ll >> 4;
    int sR = tid >> 2, sKg = (tid & 3) * 8;

    f32x4 acc[4][4] = {};

    for (int k0 = 0; k0 < K; k0 += 32) {
        const bf16* ap0 = A  + (size_t)(rowBase + sR) * K + k0 + sKg;
        const bf16* ap1 = A  + (size_t)(rowBase + 64 + sR) * K + k0 + sKg;
        const bf16* bp0 = Wt + (size_t)(colBase + sR) * K + k0 + sKg;
        const bf16* bp1 = Wt + (size_t)(colBase + 64 + sR) * K + k0 + sKg;
        *(bf16x8*)&As[sR][sKg]      = *(const bf16x8*)ap0;
        *(bf16x8*)&As[sR + 64][sKg] = *(const bf16x8*)ap1;
        *(bf16x8*)&Bs[sR][sKg]      = *(const bf16x8*)bp0;
        *(bf16x8*)&Bs[sR + 64][sKg] = *(const bf16x8*)bp1;
        __syncthreads();
        bf16x8 af[4], bfv[4];
#pragma unroll
        for (int i = 0; i < 4; ++i) af[i]  = *(const bf16x8*)&As[wr + i * 16 + lRow][quad * 8];
#pragma unroll
        for (int j = 0; j < 4; ++j) bfv[j] = *(const bf16x8*)&Bs[wc + j * 16 + lRow][quad * 8];
#pragma unroll
        for (int i = 0; i < 4; ++i)
#pragma unroll
            for (int j = 0; j < 4; ++j)
                acc[i][j] = __builtin_amdgcn_mfma_f32_16x16x32_bf16(af[i], bfv[j], acc[i][j], 0, 0, 0);
        __syncthreads();
    }

#pragma unroll
    for (int j = 0; j < 4; ++j) {
        int col = colBase + wc + j * 16 + lRow;
        float bv = ldx(bias, col, isbf);
#pragma unroll
        for (int i = 0; i < 4; ++i) {
            int r0 = rowBase + wr + i * 16 + quad * 4;
#pragma unroll
            for (int r = 0; r < 4; ++r) {
                float v = acc[i][j][r] + bv;
                if (ACT == 1) v = v / (1.f + __expf(-v));
                int row = r0 + r;
                if (RESADD) res[(size_t)row * 512 + col] += alpha * v;
                else        Cb[(size_t)row * M + col] = f2b(v);
            }
        }
    }
}

// ---------------- MFMA fused attention ----------------
// grid (S/16, H, nb), 256 thr. Q,K,O: (nb,1024,512); Vt: (nb,512,1024). O may alias Q.
__global__ __launch_bounds__(256) void fattn_kernel(const bf16* __restrict__ Q,
                                                    const bf16* __restrict__ K,
                                                    const bf16* __restrict__ Vt,
                                                    bf16* __restrict__ O) {
    __shared__ float sc[16][1028];          // scores f32 (aliased by Opart in phase 3)
    __shared__ bf16  P[16][1040];           // probs bf16
    __shared__ float red[16][16];
    __shared__ float rowm[16], rowinv[16];

    int qt = blockIdx.x, h = blockIdx.y, b = blockIdx.z;
    int tid = threadIdx.x;
    int wv = tid >> 6, ll = tid & 63, lane = ll & 15, quad = ll >> 4;
    size_t bOff = (size_t)b * 1024 * 512;
    int q0 = qt * 16;

    // A fragments (Q rows) once: A[m=lane][k=half*32+quad*8+j]
    const bf16* Qb = Q + bOff + (size_t)q0 * 512 + h * 64;
    bf16x8 aF0 = *(const bf16x8*)(Qb + (size_t)lane * 512 + quad * 8);
    bf16x8 aF1 = *(const bf16x8*)(Qb + (size_t)lane * 512 + 32 + quad * 8);

    // ---- phase 1: scores = Q K^T * 0.125; wave wv covers keys [wv*256, wv*256+256)
    const bf16* Kb = K + bOff + h * 64;
#pragma unroll
    for (int c = 0; c < 16; ++c) {
        int k0 = wv * 256 + c * 16;
        const bf16* kp = Kb + (size_t)(k0 + lane) * 512;
        f32x4 s = {0.f, 0.f, 0.f, 0.f};
        s = __builtin_amdgcn_mfma_f32_16x16x32_bf16(aF0, *(const bf16x8*)(kp + quad * 8), s, 0, 0, 0);
        s = __builtin_amdgcn_mfma_f32_16x16x32_bf16(aF1, *(const bf16x8*)(kp + 32 + quad * 8), s, 0, 0, 0);
#pragma unroll
        for (int r = 0; r < 4; ++r) sc[quad * 4 + r][k0 + lane] = s[r] * 0.125f;
    }
    __syncthreads();

    // ---- phase 2: softmax over 1024 per row; thread (r=tid>>4, c=tid&15) scans 64
    int r = tid >> 4, c16 = tid & 15;
    float m = -1e30f;
#pragma unroll 8
    for (int i = 0; i < 64; ++i) m = fmaxf(m, sc[r][c16 + 16 * i]);
    red[r][c16] = m;
    __syncthreads();
    if (c16 == 0) {
        float mm = red[r][0];
#pragma unroll
        for (int i = 1; i < 16; ++i) mm = fmaxf(mm, red[r][i]);
        rowm[r] = mm;
    }
    __syncthreads();
    float mm = rowm[r];
    float sum = 0.f;
#pragma unroll 8
    for (int i = 0; i < 64; ++i) {
        float e = __expf(sc[r][c16 + 16 * i] - mm);
        P[r][c16 + 16 * i] = f2b(e);
        sum += e;
    }
    red[r][c16] = sum;
    __syncthreads();
    if (c16 == 0) {
        float ss = red[r][0];
#pragma unroll
        for (int i = 1; i < 16; ++i) ss += red[r][i];
        rowinv[r] = 1.f / ss;
    }
    __syncthreads();

    // ---- phase 3: O = P V ; wave wv covers keys [wv*256, +256), all 64 dims
    const bf16* Vb = Vt + bOff + (size_t)(h * 64) * 1024;
    f32x4 oacc[4] = {};
#pragma unroll
    for (int ch = 0; ch < 8; ++ch) {
        int k0 = wv * 256 + ch * 32;
        bf16x8 pa = *(const bf16x8*)&P[lane][k0 + quad * 8];
#pragma unroll
        for (int g = 0; g < 4; ++g) {
            const bf16* vp = Vb + (size_t)(g * 16 + lane) * 1024 + k0 + quad * 8;
            oacc[g] = __builtin_amdgcn_mfma_f32_16x16x32_bf16(pa, *(const bf16x8*)vp, oacc[g], 0, 0, 0);
        }
    }
    // partial O per wave -> LDS (aliases sc, dead now), stride 68 to avoid conflicts
    float* Op = (float*)sc;   // [wv][16][68]
#pragma unroll
    for (int g = 0; g < 4; ++g)
#pragma unroll
        for (int r2 = 0; r2 < 4; ++r2)
            Op[(size_t)wv * 16 * 68 + (quad * 4 + r2) * 68 + g * 16 + lane] = oacc[g][r2];
    __syncthreads();

    // combine 4 waves + scale by rowinv; 1024 outputs, 4 per thread
#pragma unroll
    for (int u = 0; u < 4; ++u) {
        int flat = tid * 4 + u;
        int rr = flat >> 6, d = flat & 63;
        float v = Op[(size_t)0 * 16 * 68 + rr * 68 + d] + Op[(size_t)1 * 16 * 68 + rr * 68 + d]
                + Op[(size_t)2 * 16 * 68 + rr * 68 + d] + Op[(size_t)3 * 16 * 68 + rr * 68 + d];
        O[bOff + (size_t)(q0 + rr) * 512 + h * 64 + d] = f2b(v * rowinv[rr]);
    }
}

// ---------------- depthwise conv + BN + SiLU ----------------
__global__ __launch_bounds__(256) void dwconv_kernel(const bf16* __restrict__ X,
                                                     const void* __restrict__ w,
                                                     const void* __restrict__ dwb,
                                                     const void* __restrict__ bng,
                                                     const void* __restrict__ bnb,
                                                     const void* __restrict__ bnm,
                                                     const void* __restrict__ bnv,
                                                     bf16* __restrict__ Out, const int* flag) {
    bool isbf = (*flag != 0);
    int s = blockIdx.x, tid = threadIdx.x;
    size_t bOff = (size_t)blockIdx.y * 1024 * 512;
    int c0 = tid * 2;
    float a0 = 0.f, a1 = 0.f;
#pragma unroll
    for (int k = 0; k < 31; ++k) {
        int sp = s + k - 15;
        if (sp >= 0 && sp < 1024) {
            const bf16* xp = X + bOff + (size_t)sp * 512 + c0;
            a0 += b2f(xp[0]) * ldx(w, (size_t)c0 * 31 + k, isbf);
            a1 += b2f(xp[1]) * ldx(w, (size_t)(c0 + 1) * 31 + k, isbf);
        }
    }
    float o[2] = {a0, a1};
#pragma unroll
    for (int u = 0; u < 2; ++u) {
        int c = c0 + u;
        float v = o[u] + ldx(dwb, c, isbf);
        float iv = rsqrtf(ldx(bnv, c, isbf) + LN_EPS);
        v = (v - ldx(bnm, c, isbf)) * iv * ldx(bng, c, isbf) + ldx(bnb, c, isbf);
        v = v / (1.f + __expf(-v));
        Out[bOff + (size_t)s * 512 + c] = f2b(v);
    }
}

extern "C" void kernel_launch(void* const* d_in, const int* in_sizes, int n_in,
                              void* d_out, int out_size, void* d_ws, size_t ws_size,
                              hipStream_t stream) {
    const int B = 8, S = 1024, D = 512, F = 2048, H = 8;
    const int N = B * S;
    const size_t ND = (size_t)N * D;
    if (n_in < 37) return;

    int idx = 0;
    const void* x          = d_in[idx++];
    const void* ffn1_ln_g  = d_in[idx++];
    const void* ffn1_ln_b  = d_in[idx++];
    const void* ffn1_w1    = d_in[idx++];
    const void* ffn1_b1    = d_in[idx++];
    const void* ffn1_w2    = d_in[idx++];
    const void* ffn1_b2    = d_in[idx++];
    const void* mhsa_ln_g  = d_in[idx++];
    const void* mhsa_ln_b  = d_in[idx++];
    const void* wq         = d_in[idx++];
    const void* bq         = d_in[idx++];
    const void* wk         = d_in[idx++];
    const void* bk         = d_in[idx++];
    const void* wv         = d_in[idx++];
    const void* bv         = d_in[idx++];
    const void* wo         = d_in[idx++];
    const void* bo         = d_in[idx++];
    const void* conv_ln_g  = d_in[idx++];
    const void* conv_ln_b  = d_in[idx++];
    const void* pw1_w      = d_in[idx++];
    const void* pw1_b      = d_in[idx++];
    const void* dw_w       = d_in[idx++];
    const void* dw_b       = d_in[idx++];
    const void* bn_g       = d_in[idx++];
    const void* bn_b       = d_in[idx++];
    const void* bn_mean    = d_in[idx++];
    const void* bn_var     = d_in[idx++];
    const void* pw2_w      = d_in[idx++];
    const void* pw2_b      = d_in[idx++];
    const void* ffn2_ln_g  = d_in[idx++];
    const void* ffn2_ln_b  = d_in[idx++];
    const void* ffn2_w1    = d_in[idx++];
    const void* ffn2_b1    = d_in[idx++];
    const void* ffn2_w2    = d_in[idx++];
    const void* ffn2_b2    = d_in[idx++];
    const void* final_ln_g = d_in[idx++];
    const void* final_ln_b = d_in[idx++];

    const size_t MB = 1024 * 1024;
    char* wsb  = (char*)d_ws;
    int*  flag = (int*)wsb;
    float* res = (float*)(wsb + 1024);
    bf16*  wt  = (bf16*)(wsb + 1024 + ND * 4);
    char*  scr = wsb + 1024 + ND * 4 + 4 * MB;
    size_t scrB = (ws_size > 1024 + ND * 4 + 4 * MB) ? ws_size - (1024 + ND * 4 + 4 * MB) : 0;
    int ffnRows = (scrB >= 32 * MB) ? 8192 : ((scrB >= 8 * MB) ? 2048 : 1024);
    int bI      = (scrB >= 32 * MB) ? 8    : ((scrB >= 8 * MB) ? 2    : 1);   // MHSA: 4 MB/batch
    int cI      = (scrB >= 32 * MB) ? 8    : ((scrB >= 8 * MB) ? 2    : 1);   // conv: 4 MB/batch

    bf16* h = (bf16*)d_out;

    detect_kernel<<<1, 1, 0, stream>>>(ffn1_ln_g, flag);
    to_f32_kernel<<<(int)(ND / 256), 256, 0, stream>>>(x, res, (int)ND, flag);

    auto run_ffn = [&](const void* lg, const void* lb, const void* w1, const void* b1,
                       const void* w2, const void* b2) {
        bf16* w1t = wt;
        bf16* w2t = wt + (size_t)D * F;
        transpose_kernel<<<dim3(D / 32, F / 32), dim3(32, 8), 0, stream>>>(w1, w1t, D, F, flag);
        transpose_kernel<<<dim3(F / 32, D / 32), dim3(32, 8), 0, stream>>>(w2, w2t, F, D, flag);
        ln_kernel<<<N, 256, 0, stream>>>(res, lg, lb, h, flag);
        bf16* mid = (bf16*)scr;
        for (int r0 = 0; r0 < N; r0 += ffnRows) {
            mgemm_kernel<1, 0><<<dim3(F / 128, ffnRows / 128), 256, 0, stream>>>(
                h + (size_t)r0 * D, w1t, b1, mid, nullptr, 0.f, D, F, flag);
            mgemm_kernel<0, 1><<<dim3(D / 128, ffnRows / 128), 256, 0, stream>>>(
                mid, w2t, b2, nullptr, res + (size_t)r0 * D, 0.5f, F, D, flag);
        }
    };

    // ---- FFN1 ----
    run_ffn(ffn1_ln_g, ffn1_ln_b, ffn1_w1, ffn1_b1, ffn1_w2, ffn1_b2);

    // ---- MHSA ----
    {
        bf16* qt = wt;
        bf16* kt = wt + (size_t)D * D;
        bf16* vt = wt + 2 * (size_t)D * D;
        bf16* ot = wt + 3 * (size_t)D * D;
        transpose_kernel<<<dim3(D / 32, D / 32), dim3(32, 8), 0, stream>>>(wq, qt, D, D, flag);
        transpose_kernel<<<dim3(D / 32, D / 32), dim3(32, 8), 0, stream>>>(wk, kt, D, D, flag);
        transpose_kernel<<<dim3(D / 32, D / 32), dim3(32, 8), 0, stream>>>(wv, vt, D, D, flag);
        transpose_kernel<<<dim3(D / 32, D / 32), dim3(32, 8), 0, stream>>>(wo, ot, D, D, flag);
        ln_kernel<<<N, 256, 0, stream>>>(res, mhsa_ln_g, mhsa_ln_b, h, flag);
        for (int b = 0; b < B; b += bI) {
            int rows = bI * S;
            bf16* Q  = (bf16*)scr;
            bf16* Kb = Q  + (size_t)rows * D;
            bf16* V  = Kb + (size_t)rows * D;
            bf16* Vt = V  + (size_t)rows * D;   // (bI,512,1024)
            const bf16* Ah = h + (size_t)b * S * D;
            mgemm_kernel<0, 0><<<dim3(D / 128, rows / 128), 256, 0, stream>>>(Ah, qt, bq, Q,  nullptr, 0.f, D, D, flag);
            mgemm_kernel<0, 0><<<dim3(D / 128, rows / 128), 256, 0, stream>>>(Ah, kt, bk, Kb, nullptr, 0.f, D, D, flag);
            mgemm_kernel<0, 0><<<dim3(D / 128, rows / 128), 256, 0, stream>>>(Ah, vt, bv, V,  nullptr, 0.f, D, D, flag);
            vtrans_kernel<<<dim3(S / 32, D / 32, bI), dim3(32, 8), 0, stream>>>(V, Vt);
            fattn_kernel<<<dim3(S / 16, H, bI), 256, 0, stream>>>(Q, Kb, Vt, Q);  // in-place ctx
            mgemm_kernel<0, 1><<<dim3(D / 128, rows / 128), 256, 0, stream>>>(
                Q, ot, bo, nullptr, res + (size_t)b * S * D, 1.0f, D, D, flag);
        }
    }

    // ---- Conv module ----
    {
        bf16* p1t = wt;
        bf16* p2t = wt + (size_t)D * 2 * D;
        transpose_kernel<<<dim3(D / 32, (2 * D) / 32), dim3(32, 8), 0, stream>>>(pw1_w, p1t, D, 2 * D, flag);
        transpose_kernel<<<dim3(D / 32, D / 32), dim3(32, 8), 0, stream>>>(pw2_w, p2t, D, D, flag);
        ln_kernel<<<N, 256, 0, stream>>>(res, conv_ln_g, conv_ln_b, h, flag);
        for (int b = 0; b < B; b += cI) {
            int rows = cI * S;
            bf16* u  = (bf16*)scr;
            bf16* hg = u + (size_t)rows * 2 * D;
            bf16* dw = hg + (size_t)rows * D;
            const bf16* Ah = h + (size_t)b * S * D;
            mgemm_kernel<0, 0><<<dim3((2 * D) / 128, rows / 128), 256, 0, stream>>>(
                Ah, p1t, pw1_b, u, nullptr, 0.f, D, 2 * D, flag);
            glu_kernel<<<(rows * D) / 256, 256, 0, stream>>>(u, hg, rows * D);
            dwconv_kernel<<<dim3(S, cI), 256, 0, stream>>>(hg, dw_w, dw_b, bn_g, bn_b, bn_mean, bn_var, dw, flag);
            mgemm_kernel<0, 1><<<dim3(D / 128, rows / 128), 256, 0, stream>>>(
                dw, p2t, pw2_b, nullptr, res + (size_t)b * S * D, 1.0f, D, D, flag);
        }
    }

    // ---- FFN2 ----
    run_ffn(ffn2_ln_g, ffn2_ln_b, ffn2_w1, ffn2_b1, ffn2_w2, ffn2_b2);

    // ---- final LN -> d_out ----
    ln_out_kernel<<<N, 256, 0, stream>>>(res, final_ln_g, final_ln_b, d_out, flag);
}

// Round 6
// 812.011 us; speedup vs baseline: 10.4421x; 1.3499x over previous
//
#include <hip/hip_runtime.h>
#include <hip/hip_bf16.h>
#include <cstddef>

typedef __hip_bfloat16 bf16;
typedef __attribute__((ext_vector_type(8))) short bf16x8;
typedef __attribute__((ext_vector_type(4))) float f32x4;

static __device__ __forceinline__ float b2f(bf16 v) { return __bfloat162float(v); }
static __device__ __forceinline__ bf16 f2b(float v) { return __float2bfloat16(v); }
static __device__ __forceinline__ float bits2f(unsigned short u) {
    union { unsigned int i; float f; } c; c.i = ((unsigned int)u) << 16; return c.f;
}
static __device__ __forceinline__ float ldx(const void* p, size_t i, bool isbf) {
    return isbf ? b2f(((const bf16*)p)[i]) : ((const float*)p)[i];
}

#define LN_EPS 1e-5f

// ---------------- dtype probe ----------------
__global__ void detect_kernel(const void* ones, int* flag) {
    unsigned int w = *(const unsigned int*)ones;
    *flag = (w == 0x3F803F80u) ? 1 : 0;
}

// ---------------- residual init (vectorized, n8 = n/8) ----------------
__global__ void to_f32_kernel(const void* x, float* __restrict__ y, int n8, const int* flag) {
    bool isbf = (*flag != 0);
    int i = blockIdx.x * blockDim.x + threadIdx.x;
    if (i >= n8) return;
    size_t base = (size_t)i * 8;
    if (isbf) {
        bf16x8 xv = *(const bf16x8*)((const bf16*)x + base);
#pragma unroll
        for (int u = 0; u < 8; ++u) y[base + u] = bits2f((unsigned short)xv[u]);
    } else {
        f32x4 a = *(const f32x4*)((const float*)x + base);
        f32x4 b = *(const f32x4*)((const float*)x + base + 4);
        *(f32x4*)(y + base) = a;
        *(f32x4*)(y + base + 4) = b;
    }
}

// ---------------- weight transpose: W (K x M) -> Wt (M x K) bf16 ----------------
__global__ __launch_bounds__(256) void transpose_kernel(const void* __restrict__ W,
                                                        bf16* __restrict__ Wt,
                                                        int K, int M, const int* flag) {
    bool isbf = (*flag != 0);
    __shared__ float ts[32][33];
    int kt0 = blockIdx.x * 32, mt0 = blockIdx.y * 32;
    int x = threadIdx.x, y = threadIdx.y;
    for (int yy = y; yy < 32; yy += 8)
        ts[yy][x] = ldx(W, (size_t)(kt0 + yy) * M + mt0 + x, isbf);
    __syncthreads();
    for (int yy = y; yy < 32; yy += 8)
        Wt[(size_t)(mt0 + yy) * K + kt0 + x] = f2b(ts[x][yy]);
}

// ---------------- V transpose: V (nb,1024,512) -> Vt (nb,512,1024) ----------------
__global__ __launch_bounds__(256) void vtrans_kernel(const bf16* __restrict__ V,
                                                     bf16* __restrict__ Vt) {
    __shared__ bf16 t[32][33];
    int s0 = blockIdx.x * 32, c0 = blockIdx.y * 32, b = blockIdx.z;
    int x = threadIdx.x, y = threadIdx.y;
    const bf16* Vb = V + (size_t)b * 1024 * 512;
    bf16* Vtb = Vt + (size_t)b * 512 * 1024;
    for (int yy = y; yy < 32; yy += 8)
        t[yy][x] = Vb[(size_t)(s0 + yy) * 512 + c0 + x];
    __syncthreads();
    for (int yy = y; yy < 32; yy += 8)
        Vtb[(size_t)(c0 + yy) * 1024 + s0 + x] = t[x][yy];
}

// ---------------- GLU (vectorized, n8 = rows*512/8) ----------------
__global__ void glu_kernel(const bf16* __restrict__ u, bf16* __restrict__ o, int n8) {
    int i = blockIdx.x * blockDim.x + threadIdx.x;
    if (i >= n8) return;
    size_t base = (size_t)i * 8;
    int t = (int)(base >> 9), c = (int)(base & 511);
    bf16x8 av = *(const bf16x8*)(u + (size_t)t * 1024 + c);
    bf16x8 gv = *(const bf16x8*)(u + (size_t)t * 1024 + 512 + c);
    __attribute__((aligned(16))) bf16 ov[8];
#pragma unroll
    for (int k = 0; k < 8; ++k) {
        float a = bits2f((unsigned short)av[k]);
        float g = bits2f((unsigned short)gv[k]);
        ov[k] = f2b(a / (1.f + __expf(-g)));
    }
    *(bf16x8*)(o + base) = *(bf16x8*)ov;
}

// ---------------- LayerNorm: wave per token, shuffle reduce ----------------
__global__ __launch_bounds__(256) void ln_kernel(const float* __restrict__ X,
                                                 const void* __restrict__ g,
                                                 const void* __restrict__ b,
                                                 bf16* __restrict__ O, const int* flag) {
    bool isbf = (*flag != 0);
    int tid = threadIdx.x, lane = tid & 63, wid = tid >> 6;
    int t = blockIdx.x * 4 + wid;
    const float* x = X + (size_t)t * 512 + lane * 8;
    __attribute__((aligned(16))) float v[8];
    *(f32x4*)&v[0] = *(const f32x4*)x;
    *(f32x4*)&v[4] = *(const f32x4*)(x + 4);
    float s = 0.f, q = 0.f;
#pragma unroll
    for (int u = 0; u < 8; ++u) { s += v[u]; q += v[u] * v[u]; }
#pragma unroll
    for (int m = 1; m < 64; m <<= 1) { s += __shfl_xor(s, m, 64); q += __shfl_xor(q, m, 64); }
    float mean = s * (1.f / 512.f);
    float var  = q * (1.f / 512.f) - mean * mean;
    float sc = rsqrtf(var + LN_EPS);
    __attribute__((aligned(16))) bf16 ov[8];
#pragma unroll
    for (int u = 0; u < 8; ++u)
        ov[u] = f2b((v[u] - mean) * sc * ldx(g, lane * 8 + u, isbf) + ldx(b, lane * 8 + u, isbf));
    *(bf16x8*)(O + (size_t)t * 512 + lane * 8) = *(bf16x8*)ov;
}

__global__ __launch_bounds__(256) void ln_out_kernel(const float* __restrict__ X,
                                                     const void* __restrict__ g,
                                                     const void* __restrict__ b,
                                                     void* __restrict__ O, const int* flag) {
    bool isbf = (*flag != 0);
    int tid = threadIdx.x, lane = tid & 63, wid = tid >> 6;
    int t = blockIdx.x * 4 + wid;
    const float* x = X + (size_t)t * 512 + lane * 8;
    __attribute__((aligned(16))) float v[8];
    *(f32x4*)&v[0] = *(const f32x4*)x;
    *(f32x4*)&v[4] = *(const f32x4*)(x + 4);
    float s = 0.f, q = 0.f;
#pragma unroll
    for (int u = 0; u < 8; ++u) { s += v[u]; q += v[u] * v[u]; }
#pragma unroll
    for (int m = 1; m < 64; m <<= 1) { s += __shfl_xor(s, m, 64); q += __shfl_xor(q, m, 64); }
    float mean = s * (1.f / 512.f);
    float var  = q * (1.f / 512.f) - mean * mean;
    float sc = rsqrtf(var + LN_EPS);
    float r[8];
#pragma unroll
    for (int u = 0; u < 8; ++u)
        r[u] = (v[u] - mean) * sc * ldx(g, lane * 8 + u, isbf) + ldx(b, lane * 8 + u, isbf);
    size_t off = (size_t)t * 512 + lane * 8;
    if (isbf) {
        __attribute__((aligned(16))) bf16 ov[8];
#pragma unroll
        for (int u = 0; u < 8; ++u) ov[u] = f2b(r[u]);
        *(bf16x8*)((bf16*)O + off) = *(bf16x8*)ov;
    } else {
        *(f32x4*)((float*)O + off) = *(f32x4*)&r[0];
        *(f32x4*)((float*)O + off + 4) = *(f32x4*)&r[4];
    }
}

// ---------------- MFMA GEMM (128x128 tile, BK=32) ----------------
template <int ACT, int RESADD>
__global__ __launch_bounds__(256) void mgemm_kernel(const bf16* __restrict__ A,
                                                    const bf16* __restrict__ Wt,
                                                    const void* __restrict__ bias,
                                                    bf16* __restrict__ Cb,
                                                    float* __restrict__ res, float alpha,
                                                    int K, int M, const int* flag) {
    bool isbf = (*flag != 0);
    __shared__ short As[128][40];
    __shared__ short Bs[128][40];
    int tid = threadIdx.x;
    int rowBase = blockIdx.y * 128, colBase = blockIdx.x * 128;
    int ll = tid & 63, wv = tid >> 6;
    int wr = (wv & 1) * 64, wc = (wv >> 1) * 64;
    int lRow = ll & 15, quad = ll >> 4;
    int sR = tid >> 2, sKg = (tid & 3) * 8;

    f32x4 acc[4][4] = {};

    for (int k0 = 0; k0 < K; k0 += 32) {
        const bf16* ap0 = A  + (size_t)(rowBase + sR) * K + k0 + sKg;
        const bf16* ap1 = A  + (size_t)(rowBase + 64 + sR) * K + k0 + sKg;
        const bf16* bp0 = Wt + (size_t)(colBase + sR) * K + k0 + sKg;
        const bf16* bp1 = Wt + (size_t)(colBase + 64 + sR) * K + k0 + sKg;
        *(bf16x8*)&As[sR][sKg]      = *(const bf16x8*)ap0;
        *(bf16x8*)&As[sR + 64][sKg] = *(const bf16x8*)ap1;
        *(bf16x8*)&Bs[sR][sKg]      = *(const bf16x8*)bp0;
        *(bf16x8*)&Bs[sR + 64][sKg] = *(const bf16x8*)bp1;
        __syncthreads();
        bf16x8 af[4], bfv[4];
#pragma unroll
        for (int i = 0; i < 4; ++i) af[i]  = *(const bf16x8*)&As[wr + i * 16 + lRow][quad * 8];
#pragma unroll
        for (int j = 0; j < 4; ++j) bfv[j] = *(const bf16x8*)&Bs[wc + j * 16 + lRow][quad * 8];
#pragma unroll
        for (int i = 0; i < 4; ++i)
#pragma unroll
            for (int j = 0; j < 4; ++j)
                acc[i][j] = __builtin_amdgcn_mfma_f32_16x16x32_bf16(af[i], bfv[j], acc[i][j], 0, 0, 0);
        __syncthreads();
    }

#pragma unroll
    for (int j = 0; j < 4; ++j) {
        int col = colBase + wc + j * 16 + lRow;
        float bv = ldx(bias, col, isbf);
#pragma unroll
        for (int i = 0; i < 4; ++i) {
            int r0 = rowBase + wr + i * 16 + quad * 4;
#pragma unroll
            for (int r = 0; r < 4; ++r) {
                float v = acc[i][j][r] + bv;
                if (ACT == 1) v = v / (1.f + __expf(-v));
                int row = r0 + r;
                if (RESADD) res[(size_t)row * 512 + col] += alpha * v;
                else        Cb[(size_t)row * M + col] = f2b(v);
            }
        }
    }
}

// ---------------- MFMA fused attention ----------------
__global__ __launch_bounds__(256) void fattn_kernel(const bf16* __restrict__ Q,
                                                    const bf16* __restrict__ K,
                                                    const bf16* __restrict__ Vt,
                                                    bf16* __restrict__ O) {
    __shared__ float sc[16][1028];
    __shared__ bf16  P[16][1040];
    __shared__ float red[16][16];
    __shared__ float rowm[16], rowinv[16];

    int qt = blockIdx.x, h = blockIdx.y, b = blockIdx.z;
    int tid = threadIdx.x;
    int wv = tid >> 6, ll = tid & 63, lane = ll & 15, quad = ll >> 4;
    size_t bOff = (size_t)b * 1024 * 512;
    int q0 = qt * 16;

    const bf16* Qb = Q + bOff + (size_t)q0 * 512 + h * 64;
    bf16x8 aF0 = *(const bf16x8*)(Qb + (size_t)lane * 512 + quad * 8);
    bf16x8 aF1 = *(const bf16x8*)(Qb + (size_t)lane * 512 + 32 + quad * 8);

    const bf16* Kb = K + bOff + h * 64;
#pragma unroll
    for (int c = 0; c < 16; ++c) {
        int k0 = wv * 256 + c * 16;
        const bf16* kp = Kb + (size_t)(k0 + lane) * 512;
        f32x4 s = {0.f, 0.f, 0.f, 0.f};
        s = __builtin_amdgcn_mfma_f32_16x16x32_bf16(aF0, *(const bf16x8*)(kp + quad * 8), s, 0, 0, 0);
        s = __builtin_amdgcn_mfma_f32_16x16x32_bf16(aF1, *(const bf16x8*)(kp + 32 + quad * 8), s, 0, 0, 0);
#pragma unroll
        for (int r = 0; r < 4; ++r) sc[quad * 4 + r][k0 + lane] = s[r] * 0.125f;
    }
    __syncthreads();

    int r = tid >> 4, c16 = tid & 15;
    float m = -1e30f;
#pragma unroll 8
    for (int i = 0; i < 64; ++i) m = fmaxf(m, sc[r][c16 + 16 * i]);
    red[r][c16] = m;
    __syncthreads();
    if (c16 == 0) {
        float mm = red[r][0];
#pragma unroll
        for (int i = 1; i < 16; ++i) mm = fmaxf(mm, red[r][i]);
        rowm[r] = mm;
    }
    __syncthreads();
    float mm = rowm[r];
    float sum = 0.f;
#pragma unroll 8
    for (int i = 0; i < 64; ++i) {
        float e = __expf(sc[r][c16 + 16 * i] - mm);
        P[r][c16 + 16 * i] = f2b(e);
        sum += e;
    }
    red[r][c16] = sum;
    __syncthreads();
    if (c16 == 0) {
        float ss = red[r][0];
#pragma unroll
        for (int i = 1; i < 16; ++i) ss += red[r][i];
        rowinv[r] = 1.f / ss;
    }
    __syncthreads();

    const bf16* Vb = Vt + bOff + (size_t)(h * 64) * 1024;
    f32x4 oacc[4] = {};
#pragma unroll
    for (int ch = 0; ch < 8; ++ch) {
        int k0 = wv * 256 + ch * 32;
        bf16x8 pa = *(const bf16x8*)&P[lane][k0 + quad * 8];
#pragma unroll
        for (int g = 0; g < 4; ++g) {
            const bf16* vp = Vb + (size_t)(g * 16 + lane) * 1024 + k0 + quad * 8;
            oacc[g] = __builtin_amdgcn_mfma_f32_16x16x32_bf16(pa, *(const bf16x8*)vp, oacc[g], 0, 0, 0);
        }
    }
    float* Op = (float*)sc;
#pragma unroll
    for (int g = 0; g < 4; ++g)
#pragma unroll
        for (int r2 = 0; r2 < 4; ++r2)
            Op[(size_t)wv * 16 * 68 + (quad * 4 + r2) * 68 + g * 16 + lane] = oacc[g][r2];
    __syncthreads();

#pragma unroll
    for (int u = 0; u < 4; ++u) {
        int flat = tid * 4 + u;
        int rr = flat >> 6, d = flat & 63;
        float v = Op[(size_t)0 * 16 * 68 + rr * 68 + d] + Op[(size_t)1 * 16 * 68 + rr * 68 + d]
                + Op[(size_t)2 * 16 * 68 + rr * 68 + d] + Op[(size_t)3 * 16 * 68 + rr * 68 + d];
        O[bOff + (size_t)(q0 + rr) * 512 + h * 64 + d] = f2b(v * rowinv[rr]);
    }
}

// ---------------- depthwise conv prep: wT[k][c] bf16 + BN folded scale/shift ----------------
__global__ void dwprep_kernel(const void* __restrict__ w, const void* __restrict__ dwb,
                              const void* __restrict__ bng, const void* __restrict__ bnb,
                              const void* __restrict__ bnm, const void* __restrict__ bnv,
                              bf16* __restrict__ wT, float* __restrict__ scl,
                              float* __restrict__ sft, const int* flag) {
    bool isbf = (*flag != 0);
    int c = blockIdx.x * blockDim.x + threadIdx.x;
    if (c >= 512) return;
    for (int k = 0; k < 31; ++k) wT[k * 512 + c] = f2b(ldx(w, (size_t)c * 31 + k, isbf));
    float s = ldx(bng, c, isbf) * rsqrtf(ldx(bnv, c, isbf) + LN_EPS);
    scl[c] = s;
    sft[c] = (ldx(dwb, c, isbf) - ldx(bnm, c, isbf)) * s + ldx(bnb, c, isbf);
}

// ---------------- depthwise conv + BN + SiLU (register-tiled) ----------------
// grid (S/16, B); wave wv handles 4 s-positions x 512 channels, lane owns 8 channels.
__global__ __launch_bounds__(256) void dwconv_kernel(const bf16* __restrict__ X,
                                                     const bf16* __restrict__ wT,
                                                     const float* __restrict__ scl,
                                                     const float* __restrict__ sft,
                                                     bf16* __restrict__ Out) {
    __shared__ bf16 wl[31 * 512];
    __shared__ float sl[512], fl[512];
    int tid = threadIdx.x;
    for (int i = tid; i < (31 * 512) / 8; i += 256)
        *(bf16x8*)&wl[i * 8] = *(const bf16x8*)&wT[i * 8];
    sl[tid] = scl[tid]; sl[tid + 256] = scl[tid + 256];
    fl[tid] = sft[tid]; fl[tid + 256] = sft[tid + 256];
    __syncthreads();

    int lane = tid & 63, sg = tid >> 6;
    int c = lane * 8;
    size_t bOff = (size_t)blockIdx.y * 1024 * 512;
    int sb = blockIdx.x * 16 + sg * 4;

    float acc[4][8] = {};
    for (int kk = 0; kk < 34; ++kk) {
        int sp = sb + kk - 15;                    // wave-uniform
        if (sp < 0 || sp >= 1024) continue;
        bf16x8 xr = *(const bf16x8*)(X + bOff + (size_t)sp * 512 + c);
        float xv[8];
#pragma unroll
        for (int u = 0; u < 8; ++u) xv[u] = bits2f((unsigned short)xr[u]);
#pragma unroll
        for (int o = 0; o < 4; ++o) {
            int kw = kk - o;                      // wave-uniform
            if (kw < 0 || kw > 30) continue;
            bf16x8 wv8 = *(const bf16x8*)&wl[kw * 512 + c];
#pragma unroll
            for (int u = 0; u < 8; ++u) acc[o][u] += xv[u] * bits2f((unsigned short)wv8[u]);
        }
    }
#pragma unroll
    for (int o = 0; o < 4; ++o) {
        __attribute__((aligned(16))) bf16 ov[8];
#pragma unroll
        for (int u = 0; u < 8; ++u) {
            float v = acc[o][u] * sl[c + u] + fl[c + u];
            v = v / (1.f + __expf(-v));
            ov[u] = f2b(v);
        }
        *(bf16x8*)(Out + bOff + (size_t)(sb + o) * 512 + c) = *(bf16x8*)ov;
    }
}

extern "C" void kernel_launch(void* const* d_in, const int* in_sizes, int n_in,
                              void* d_out, int out_size, void* d_ws, size_t ws_size,
                              hipStream_t stream) {
    const int B = 8, S = 1024, D = 512, F = 2048, H = 8;
    const int N = B * S;
    const size_t ND = (size_t)N * D;
    if (n_in < 37) return;

    int idx = 0;
    const void* x          = d_in[idx++];
    const void* ffn1_ln_g  = d_in[idx++];
    const void* ffn1_ln_b  = d_in[idx++];
    const void* ffn1_w1    = d_in[idx++];
    const void* ffn1_b1    = d_in[idx++];
    const void* ffn1_w2    = d_in[idx++];
    const void* ffn1_b2    = d_in[idx++];
    const void* mhsa_ln_g  = d_in[idx++];
    const void* mhsa_ln_b  = d_in[idx++];
    const void* wq         = d_in[idx++];
    const void* bq         = d_in[idx++];
    const void* wk         = d_in[idx++];
    const void* bk         = d_in[idx++];
    const void* wv         = d_in[idx++];
    const void* bv         = d_in[idx++];
    const void* wo         = d_in[idx++];
    const void* bo         = d_in[idx++];
    const void* conv_ln_g  = d_in[idx++];
    const void* conv_ln_b  = d_in[idx++];
    const void* pw1_w      = d_in[idx++];
    const void* pw1_b      = d_in[idx++];
    const void* dw_w       = d_in[idx++];
    const void* dw_b       = d_in[idx++];
    const void* bn_g       = d_in[idx++];
    const void* bn_b       = d_in[idx++];
    const void* bn_mean    = d_in[idx++];
    const void* bn_var     = d_in[idx++];
    const void* pw2_w      = d_in[idx++];
    const void* pw2_b      = d_in[idx++];
    const void* ffn2_ln_g  = d_in[idx++];
    const void* ffn2_ln_b  = d_in[idx++];
    const void* ffn2_w1    = d_in[idx++];
    const void* ffn2_b1    = d_in[idx++];
    const void* ffn2_w2    = d_in[idx++];
    const void* ffn2_b2    = d_in[idx++];
    const void* final_ln_g = d_in[idx++];
    const void* final_ln_b = d_in[idx++];

    const size_t MB = 1024 * 1024;
    char* wsb  = (char*)d_ws;
    int*  flag = (int*)wsb;
    float* res = (float*)(wsb + 1024);
    bf16*  wt  = (bf16*)(wsb + 1024 + ND * 4);
    char*  dwr = wsb + 1024 + ND * 4 + 4 * MB;     // 64 KB dwconv params
    bf16*  dwT  = (bf16*)dwr;                      // 31*512 bf16
    float* dscl = (float*)(dwr + 32768);
    float* dsft = dscl + 512;
    char*  scr = dwr + 65536;
    size_t base = 1024 + ND * 4 + 4 * MB + 65536;
    size_t scrB = (ws_size > base) ? ws_size - base : 0;
    int ffnRows = (scrB >= 32 * MB) ? 8192 : ((scrB >= 8 * MB) ? 2048 : 1024);
    int bI      = (scrB >= 32 * MB) ? 8    : ((scrB >= 8 * MB) ? 2    : 1);
    int cI      = (scrB >= 32 * MB) ? 8    : ((scrB >= 8 * MB) ? 2    : 1);

    bf16* h = (bf16*)d_out;

    detect_kernel<<<1, 1, 0, stream>>>(ffn1_ln_g, flag);
    to_f32_kernel<<<(int)(ND / 8 / 256), 256, 0, stream>>>(x, res, (int)(ND / 8), flag);

    auto run_ffn = [&](const void* lg, const void* lb, const void* w1, const void* b1,
                       const void* w2, const void* b2) {
        bf16* w1t = wt;
        bf16* w2t = wt + (size_t)D * F;
        transpose_kernel<<<dim3(D / 32, F / 32), dim3(32, 8), 0, stream>>>(w1, w1t, D, F, flag);
        transpose_kernel<<<dim3(F / 32, D / 32), dim3(32, 8), 0, stream>>>(w2, w2t, F, D, flag);
        ln_kernel<<<N / 4, 256, 0, stream>>>(res, lg, lb, h, flag);
        bf16* mid = (bf16*)scr;
        for (int r0 = 0; r0 < N; r0 += ffnRows) {
            mgemm_kernel<1, 0><<<dim3(F / 128, ffnRows / 128), 256, 0, stream>>>(
                h + (size_t)r0 * D, w1t, b1, mid, nullptr, 0.f, D, F, flag);
            mgemm_kernel<0, 1><<<dim3(D / 128, ffnRows / 128), 256, 0, stream>>>(
                mid, w2t, b2, nullptr, res + (size_t)r0 * D, 0.5f, F, D, flag);
        }
    };

    // ---- FFN1 ----
    run_ffn(ffn1_ln_g, ffn1_ln_b, ffn1_w1, ffn1_b1, ffn1_w2, ffn1_b2);

    // ---- MHSA ----
    {
        bf16* qt = wt;
        bf16* kt = wt + (size_t)D * D;
        bf16* vt = wt + 2 * (size_t)D * D;
        bf16* ot = wt + 3 * (size_t)D * D;
        transpose_kernel<<<dim3(D / 32, D / 32), dim3(32, 8), 0, stream>>>(wq, qt, D, D, flag);
        transpose_kernel<<<dim3(D / 32, D / 32), dim3(32, 8), 0, stream>>>(wk, kt, D, D, flag);
        transpose_kernel<<<dim3(D / 32, D / 32), dim3(32, 8), 0, stream>>>(wv, vt, D, D, flag);
        transpose_kernel<<<dim3(D / 32, D / 32), dim3(32, 8), 0, stream>>>(wo, ot, D, D, flag);
        ln_kernel<<<N / 4, 256, 0, stream>>>(res, mhsa_ln_g, mhsa_ln_b, h, flag);
        for (int b = 0; b < B; b += bI) {
            int rows = bI * S;
            bf16* Q  = (bf16*)scr;
            bf16* Kb = Q  + (size_t)rows * D;
            bf16* V  = Kb + (size_t)rows * D;
            bf16* Vt = V  + (size_t)rows * D;
            const bf16* Ah = h + (size_t)b * S * D;
            mgemm_kernel<0, 0><<<dim3(D / 128, rows / 128), 256, 0, stream>>>(Ah, qt, bq, Q,  nullptr, 0.f, D, D, flag);
            mgemm_kernel<0, 0><<<dim3(D / 128, rows / 128), 256, 0, stream>>>(Ah, kt, bk, Kb, nullptr, 0.f, D, D, flag);
            mgemm_kernel<0, 0><<<dim3(D / 128, rows / 128), 256, 0, stream>>>(Ah, vt, bv, V,  nullptr, 0.f, D, D, flag);
            vtrans_kernel<<<dim3(S / 32, D / 32, bI), dim3(32, 8), 0, stream>>>(V, Vt);
            fattn_kernel<<<dim3(S / 16, H, bI), 256, 0, stream>>>(Q, Kb, Vt, Q);
            mgemm_kernel<0, 1><<<dim3(D / 128, rows / 128), 256, 0, stream>>>(
                Q, ot, bo, nullptr, res + (size_t)b * S * D, 1.0f, D, D, flag);
        }
    }

    // ---- Conv module ----
    {
        bf16* p1t = wt;
        bf16* p2t = wt + (size_t)D * 2 * D;
        transpose_kernel<<<dim3(D / 32, (2 * D) / 32), dim3(32, 8), 0, stream>>>(pw1_w, p1t, D, 2 * D, flag);
        transpose_kernel<<<dim3(D / 32, D / 32), dim3(32, 8), 0, stream>>>(pw2_w, p2t, D, D, flag);
        dwprep_kernel<<<2, 256, 0, stream>>>(dw_w, dw_b, bn_g, bn_b, bn_mean, bn_var, dwT, dscl, dsft, flag);
        ln_kernel<<<N / 4, 256, 0, stream>>>(res, conv_ln_g, conv_ln_b, h, flag);
        for (int b = 0; b < B; b += cI) {
            int rows = cI * S;
            bf16* u  = (bf16*)scr;
            bf16* hg = u + (size_t)rows * 2 * D;
            bf16* dw = hg + (size_t)rows * D;
            const bf16* Ah = h + (size_t)b * S * D;
            mgemm_kernel<0, 0><<<dim3((2 * D) / 128, rows / 128), 256, 0, stream>>>(
                Ah, p1t, pw1_b, u, nullptr, 0.f, D, 2 * D, flag);
            glu_kernel<<<(rows * D / 8) / 256, 256, 0, stream>>>(u, hg, rows * D / 8);
            dwconv_kernel<<<dim3(S / 16, cI), 256, 0, stream>>>(hg, dwT, dscl, dsft, dw);
            mgemm_kernel<0, 1><<<dim3(D / 128, rows / 128), 256, 0, stream>>>(
                dw, p2t, pw2_b, nullptr, res + (size_t)b * S * D, 1.0f, D, D, flag);
        }
    }

    // ---- FFN2 ----
    run_ffn(ffn2_ln_g, ffn2_ln_b, ffn2_w1, ffn2_b1, ffn2_w2, ffn2_b2);

    // ---- final LN -> d_out ----
    ln_out_kernel<<<N / 4, 256, 0, stream>>>(res, final_ln_g, final_ln_b, d_out, flag);
}

// Round 7
// 718.307 us; speedup vs baseline: 11.8043x; 1.1305x over previous
//
#include <hip/hip_runtime.h>
#include <hip/hip_bf16.h>
#include <cstddef>

typedef __hip_bfloat16 bf16;
typedef __attribute__((ext_vector_type(8))) short bf16x8;
typedef __attribute__((ext_vector_type(4))) float f32x4;

static __device__ __forceinline__ float b2f(bf16 v) { return __bfloat162float(v); }
static __device__ __forceinline__ bf16 f2b(float v) { return __float2bfloat16(v); }
static __device__ __forceinline__ float bits2f(unsigned short u) {
    union { unsigned int i; float f; } c; c.i = ((unsigned int)u) << 16; return c.f;
}
static __device__ __forceinline__ unsigned int f2bu(float v) {
    union { bf16 b; unsigned short u; } c; c.b = f2b(v); return (unsigned int)c.u;
}
static __device__ __forceinline__ float ldx(const void* p, size_t i, bool isbf) {
    return isbf ? b2f(((const bf16*)p)[i]) : ((const float*)p)[i];
}

#define LN_EPS 1e-5f

// ---------------- dtype probe ----------------
__global__ void detect_kernel(const void* ones, int* flag) {
    unsigned int w = *(const unsigned int*)ones;
    *flag = (w == 0x3F803F80u) ? 1 : 0;
}

// ---------------- residual init (vectorized, n8 = n/8) ----------------
__global__ void to_f32_kernel(const void* x, float* __restrict__ y, int n8, const int* flag) {
    bool isbf = (*flag != 0);
    int i = blockIdx.x * blockDim.x + threadIdx.x;
    if (i >= n8) return;
    size_t base = (size_t)i * 8;
    if (isbf) {
        bf16x8 xv = *(const bf16x8*)((const bf16*)x + base);
#pragma unroll
        for (int u = 0; u < 8; ++u) y[base + u] = bits2f((unsigned short)xv[u]);
    } else {
        f32x4 a = *(const f32x4*)((const float*)x + base);
        f32x4 b = *(const f32x4*)((const float*)x + base + 4);
        *(f32x4*)(y + base) = a;
        *(f32x4*)(y + base + 4) = b;
    }
}

// ---------------- weight transpose: W (K x M) -> Wt (M x K) bf16 ----------------
__global__ __launch_bounds__(256) void transpose_kernel(const void* __restrict__ W,
                                                        bf16* __restrict__ Wt,
                                                        int K, int M, const int* flag) {
    bool isbf = (*flag != 0);
    __shared__ float ts[32][33];
    int kt0 = blockIdx.x * 32, mt0 = blockIdx.y * 32;
    int x = threadIdx.x, y = threadIdx.y;
    for (int yy = y; yy < 32; yy += 8)
        ts[yy][x] = ldx(W, (size_t)(kt0 + yy) * M + mt0 + x, isbf);
    __syncthreads();
    for (int yy = y; yy < 32; yy += 8)
        Wt[(size_t)(mt0 + yy) * K + kt0 + x] = f2b(ts[x][yy]);
}

// ---------------- V transpose: V (nb,1024,512) -> Vt (nb,512,1024) ----------------
__global__ __launch_bounds__(256) void vtrans_kernel(const bf16* __restrict__ V,
                                                     bf16* __restrict__ Vt) {
    __shared__ bf16 t[32][33];
    int s0 = blockIdx.x * 32, c0 = blockIdx.y * 32, b = blockIdx.z;
    int x = threadIdx.x, y = threadIdx.y;
    const bf16* Vb = V + (size_t)b * 1024 * 512;
    bf16* Vtb = Vt + (size_t)b * 512 * 1024;
    for (int yy = y; yy < 32; yy += 8)
        t[yy][x] = Vb[(size_t)(s0 + yy) * 512 + c0 + x];
    __syncthreads();
    for (int yy = y; yy < 32; yy += 8)
        Vtb[(size_t)(c0 + yy) * 1024 + s0 + x] = t[x][yy];
}

// ---------------- GLU (vectorized, n8 = rows*512/8) ----------------
__global__ void glu_kernel(const bf16* __restrict__ u, bf16* __restrict__ o, int n8) {
    int i = blockIdx.x * blockDim.x + threadIdx.x;
    if (i >= n8) return;
    size_t base = (size_t)i * 8;
    int t = (int)(base >> 9), c = (int)(base & 511);
    bf16x8 av = *(const bf16x8*)(u + (size_t)t * 1024 + c);
    bf16x8 gv = *(const bf16x8*)(u + (size_t)t * 1024 + 512 + c);
    __attribute__((aligned(16))) bf16 ov[8];
#pragma unroll
    for (int k = 0; k < 8; ++k) {
        float a = bits2f((unsigned short)av[k]);
        float g = bits2f((unsigned short)gv[k]);
        ov[k] = f2b(a / (1.f + __expf(-g)));
    }
    *(bf16x8*)(o + base) = *(bf16x8*)ov;
}

// ---------------- LayerNorm: wave per token, shuffle reduce ----------------
__global__ __launch_bounds__(256) void ln_kernel(const float* __restrict__ X,
                                                 const void* __restrict__ g,
                                                 const void* __restrict__ b,
                                                 bf16* __restrict__ O, const int* flag) {
    bool isbf = (*flag != 0);
    int tid = threadIdx.x, lane = tid & 63, wid = tid >> 6;
    int t = blockIdx.x * 4 + wid;
    const float* x = X + (size_t)t * 512 + lane * 8;
    __attribute__((aligned(16))) float v[8];
    *(f32x4*)&v[0] = *(const f32x4*)x;
    *(f32x4*)&v[4] = *(const f32x4*)(x + 4);
    float s = 0.f, q = 0.f;
#pragma unroll
    for (int u = 0; u < 8; ++u) { s += v[u]; q += v[u] * v[u]; }
#pragma unroll
    for (int m = 1; m < 64; m <<= 1) { s += __shfl_xor(s, m, 64); q += __shfl_xor(q, m, 64); }
    float mean = s * (1.f / 512.f);
    float var  = q * (1.f / 512.f) - mean * mean;
    float sc = rsqrtf(var + LN_EPS);
    __attribute__((aligned(16))) bf16 ov[8];
#pragma unroll
    for (int u = 0; u < 8; ++u)
        ov[u] = f2b((v[u] - mean) * sc * ldx(g, lane * 8 + u, isbf) + ldx(b, lane * 8 + u, isbf));
    *(bf16x8*)(O + (size_t)t * 512 + lane * 8) = *(bf16x8*)ov;
}

__global__ __launch_bounds__(256) void ln_out_kernel(const float* __restrict__ X,
                                                     const void* __restrict__ g,
                                                     const void* __restrict__ b,
                                                     void* __restrict__ O, const int* flag) {
    bool isbf = (*flag != 0);
    int tid = threadIdx.x, lane = tid & 63, wid = tid >> 6;
    int t = blockIdx.x * 4 + wid;
    const float* x = X + (size_t)t * 512 + lane * 8;
    __attribute__((aligned(16))) float v[8];
    *(f32x4*)&v[0] = *(const f32x4*)x;
    *(f32x4*)&v[4] = *(const f32x4*)(x + 4);
    float s = 0.f, q = 0.f;
#pragma unroll
    for (int u = 0; u < 8; ++u) { s += v[u]; q += v[u] * v[u]; }
#pragma unroll
    for (int m = 1; m < 64; m <<= 1) { s += __shfl_xor(s, m, 64); q += __shfl_xor(q, m, 64); }
    float mean = s * (1.f / 512.f);
    float var  = q * (1.f / 512.f) - mean * mean;
    float sc = rsqrtf(var + LN_EPS);
    float r[8];
#pragma unroll
    for (int u = 0; u < 8; ++u)
        r[u] = (v[u] - mean) * sc * ldx(g, lane * 8 + u, isbf) + ldx(b, lane * 8 + u, isbf);
    size_t off = (size_t)t * 512 + lane * 8;
    if (isbf) {
        __attribute__((aligned(16))) bf16 ov[8];
#pragma unroll
        for (int u = 0; u < 8; ++u) ov[u] = f2b(r[u]);
        *(bf16x8*)((bf16*)O + off) = *(bf16x8*)ov;
    } else {
        *(f32x4*)((float*)O + off) = *(f32x4*)&r[0];
        *(f32x4*)((float*)O + off + 4) = *(f32x4*)&r[4];
    }
}

// ---------------- MFMA GEMM (128x128 tile, BK=32) ----------------
template <int ACT, int RESADD>
__global__ __launch_bounds__(256) void mgemm_kernel(const bf16* __restrict__ A,
                                                    const bf16* __restrict__ Wt,
                                                    const void* __restrict__ bias,
                                                    bf16* __restrict__ Cb,
                                                    float* __restrict__ res, float alpha,
                                                    int K, int M, const int* flag) {
    bool isbf = (*flag != 0);
    __shared__ short As[128][40];
    __shared__ short Bs[128][40];
    int tid = threadIdx.x;
    int rowBase = blockIdx.y * 128, colBase = blockIdx.x * 128;
    int ll = tid & 63, wv = tid >> 6;
    int wr = (wv & 1) * 64, wc = (wv >> 1) * 64;
    int lRow = ll & 15, quad = ll >> 4;
    int sR = tid >> 2, sKg = (tid & 3) * 8;

    f32x4 acc[4][4] = {};

    for (int k0 = 0; k0 < K; k0 += 32) {
        const bf16* ap0 = A  + (size_t)(rowBase + sR) * K + k0 + sKg;
        const bf16* ap1 = A  + (size_t)(rowBase + 64 + sR) * K + k0 + sKg;
        const bf16* bp0 = Wt + (size_t)(colBase + sR) * K + k0 + sKg;
        const bf16* bp1 = Wt + (size_t)(colBase + 64 + sR) * K + k0 + sKg;
        *(bf16x8*)&As[sR][sKg]      = *(const bf16x8*)ap0;
        *(bf16x8*)&As[sR + 64][sKg] = *(const bf16x8*)ap1;
        *(bf16x8*)&Bs[sR][sKg]      = *(const bf16x8*)bp0;
        *(bf16x8*)&Bs[sR + 64][sKg] = *(const bf16x8*)bp1;
        __syncthreads();
        bf16x8 af[4], bfv[4];
#pragma unroll
        for (int i = 0; i < 4; ++i) af[i]  = *(const bf16x8*)&As[wr + i * 16 + lRow][quad * 8];
#pragma unroll
        for (int j = 0; j < 4; ++j) bfv[j] = *(const bf16x8*)&Bs[wc + j * 16 + lRow][quad * 8];
#pragma unroll
        for (int i = 0; i < 4; ++i)
#pragma unroll
            for (int j = 0; j < 4; ++j)
                acc[i][j] = __builtin_amdgcn_mfma_f32_16x16x32_bf16(af[i], bfv[j], acc[i][j], 0, 0, 0);
        __syncthreads();
    }

#pragma unroll
    for (int j = 0; j < 4; ++j) {
        int col = colBase + wc + j * 16 + lRow;
        float bv = ldx(bias, col, isbf);
#pragma unroll
        for (int i = 0; i < 4; ++i) {
            int r0 = rowBase + wr + i * 16 + quad * 4;
#pragma unroll
            for (int r = 0; r < 4; ++r) {
                float v = acc[i][j][r] + bv;
                if (ACT == 1) v = v / (1.f + __expf(-v));
                int row = r0 + r;
                if (RESADD) res[(size_t)row * 512 + col] += alpha * v;
                else        Cb[(size_t)row * M + col] = f2b(v);
            }
        }
    }
}

// ---------------- flash attention: wave-per-qtile, register online softmax ----------------
// grid (S/64, H, nb), 256 thr (4 waves, wave w -> q rows blockIdx.x*64 + w*16).
// Q,K,O: (nb,1024,512); Vt: (nb,512,1024). O may alias Q (block writes only rows/cols it read).
__global__ __launch_bounds__(256) void fattn_kernel(const bf16* __restrict__ Q,
                                                    const bf16* __restrict__ K,
                                                    const bf16* __restrict__ Vt,
                                                    bf16* __restrict__ O) {
    __shared__ float ot[4][16][68];
    int tid = threadIdx.x, wid = tid >> 6, ll = tid & 63;
    int n = ll & 15, quad = ll >> 4;
    int h = blockIdx.y, b = blockIdx.z;
    size_t bOff = (size_t)b * 1024 * 512;
    int q0 = blockIdx.x * 64 + wid * 16;

    // Q^T B-fragments (resident): B[k=dk][n=q] -> lane reads Q[q0+n][h*64 + quad*8 + j]
    const bf16* Qb = Q + bOff + h * 64;
    bf16x8 qf0 = *(const bf16x8*)(Qb + (size_t)(q0 + n) * 512 + quad * 8);
    bf16x8 qf1 = *(const bf16x8*)(Qb + (size_t)(q0 + n) * 512 + 32 + quad * 8);

    const bf16* Kb = K + bOff + h * 64;
    const bf16* Vb = Vt + bOff + (size_t)(h * 64) * 1024;

    float m = -3e38f, l = 0.f;
    f32x4 oacc[4] = {};
    int idxA = (((quad & 1) * 32) + n) * 4;   // ds_bpermute byte index
    int idxB = idxA + 64;
    bool hiC = (quad >= 2);

#pragma unroll 1
    for (int k0 = 0; k0 < 1024; k0 += 32) {
        // S^T = K·Q^T for 2 sub-chunks of 16 keys (A = K rows, m=key)
        const bf16* kp0 = Kb + (size_t)(k0 + n) * 512 + quad * 8;
        const bf16* kp1 = Kb + (size_t)(k0 + 16 + n) * 512 + quad * 8;
        f32x4 s0 = {}, s1 = {};
        s0 = __builtin_amdgcn_mfma_f32_16x16x32_bf16(*(const bf16x8*)kp0, qf0, s0, 0, 0, 0);
        s0 = __builtin_amdgcn_mfma_f32_16x16x32_bf16(*(const bf16x8*)(kp0 + 32), qf1, s0, 0, 0, 0);
        s1 = __builtin_amdgcn_mfma_f32_16x16x32_bf16(*(const bf16x8*)kp1, qf0, s1, 0, 0, 0);
        s1 = __builtin_amdgcn_mfma_f32_16x16x32_bf16(*(const bf16x8*)(kp1 + 32), qf1, s1, 0, 0, 0);
#pragma unroll
        for (int r = 0; r < 4; ++r) { s0[r] *= 0.125f; s1[r] *= 0.125f; }

        // online softmax per column q (col = n; rows = keys spread over quads)
        float cm = fmaxf(fmaxf(fmaxf(s0[0], s0[1]), fmaxf(s0[2], s0[3])),
                         fmaxf(fmaxf(s1[0], s1[1]), fmaxf(s1[2], s1[3])));
        cm = fmaxf(cm, __shfl_xor(cm, 16, 64));
        cm = fmaxf(cm, __shfl_xor(cm, 32, 64));
        float mnew = fmaxf(m, cm);
        float alpha = __expf(m - mnew);
        m = mnew;
        float p0[4], p1[4];
        float ps = 0.f;
#pragma unroll
        for (int r = 0; r < 4; ++r) {
            p0[r] = __expf(s0[r] - mnew);
            p1[r] = __expf(s1[r] - mnew);
            ps += p0[r] + p1[r];
        }
        ps += __shfl_xor(ps, 16, 64);
        ps += __shfl_xor(ps, 32, 64);
        l = l * alpha + ps;

        // pack P^T (C-layout) -> dwords, remap quads to 32-K B-fragment via bpermute
        int p0d0 = (int)(f2bu(p0[0]) | (f2bu(p0[1]) << 16));
        int p0d1 = (int)(f2bu(p0[2]) | (f2bu(p0[3]) << 16));
        int p1d0 = (int)(f2bu(p1[0]) | (f2bu(p1[1]) << 16));
        int p1d1 = (int)(f2bu(p1[2]) | (f2bu(p1[3]) << 16));
        int a0 = __builtin_amdgcn_ds_bpermute(idxA, p0d0);
        int a1 = __builtin_amdgcn_ds_bpermute(idxA, p0d1);
        int a2 = __builtin_amdgcn_ds_bpermute(idxB, p0d0);
        int a3 = __builtin_amdgcn_ds_bpermute(idxB, p0d1);
        int c0 = __builtin_amdgcn_ds_bpermute(idxA, p1d0);
        int c1 = __builtin_amdgcn_ds_bpermute(idxA, p1d1);
        int c2 = __builtin_amdgcn_ds_bpermute(idxB, p1d0);
        int c3 = __builtin_amdgcn_ds_bpermute(idxB, p1d1);
        union { int d[4]; bf16x8 v; } bf;
        bf.d[0] = hiC ? c0 : a0;
        bf.d[1] = hiC ? c1 : a1;
        bf.d[2] = hiC ? c2 : a2;
        bf.d[3] = hiC ? c3 : a3;

        // O^T += V^T · P^T  (A = Vt rows, m=dim; B = remapped P)
#pragma unroll
        for (int g = 0; g < 4; ++g) {
            const bf16* vp = Vb + (size_t)(g * 16 + n) * 1024 + k0 + quad * 8;
            f32x4 t = oacc[g];
#pragma unroll
            for (int r = 0; r < 4; ++r) t[r] *= alpha;
            oacc[g] = __builtin_amdgcn_mfma_f32_16x16x32_bf16(*(const bf16x8*)vp, bf.v, t, 0, 0, 0);
        }
    }

    // epilogue: scale by 1/l, LDS transpose, coalesced store
    float linv = 1.f / l;
#pragma unroll
    for (int g = 0; g < 4; ++g) {
        f32x4 v = oacc[g];
#pragma unroll
        for (int r = 0; r < 4; ++r) v[r] *= linv;
        *(f32x4*)&ot[wid][n][g * 16 + quad * 4] = v;
    }
    __syncthreads();
    int qq = ll >> 2, dq = ll & 3;
    const float* src = &ot[wid][qq][dq * 16];
    bf16* op = O + bOff + (size_t)(q0 + qq) * 512 + h * 64 + dq * 16;
    __attribute__((aligned(16))) bf16 ov[16];
#pragma unroll
    for (int u = 0; u < 16; ++u) ov[u] = f2b(src[u]);
    *(bf16x8*)op = *(bf16x8*)&ov[0];
    *(bf16x8*)(op + 8) = *(bf16x8*)&ov[8];
}

// ---------------- depthwise conv prep ----------------
__global__ void dwprep_kernel(const void* __restrict__ w, const void* __restrict__ dwb,
                              const void* __restrict__ bng, const void* __restrict__ bnb,
                              const void* __restrict__ bnm, const void* __restrict__ bnv,
                              bf16* __restrict__ wT, float* __restrict__ scl,
                              float* __restrict__ sft, const int* flag) {
    bool isbf = (*flag != 0);
    int c = blockIdx.x * blockDim.x + threadIdx.x;
    if (c >= 512) return;
    for (int k = 0; k < 31; ++k) wT[k * 512 + c] = f2b(ldx(w, (size_t)c * 31 + k, isbf));
    float s = ldx(bng, c, isbf) * rsqrtf(ldx(bnv, c, isbf) + LN_EPS);
    scl[c] = s;
    sft[c] = (ldx(dwb, c, isbf) - ldx(bnm, c, isbf)) * s + ldx(bnb, c, isbf);
}

// ---------------- depthwise conv + BN + SiLU (register-tiled) ----------------
__global__ __launch_bounds__(256) void dwconv_kernel(const bf16* __restrict__ X,
                                                     const bf16* __restrict__ wT,
                                                     const float* __restrict__ scl,
                                                     const float* __restrict__ sft,
                                                     bf16* __restrict__ Out) {
    __shared__ bf16 wl[31 * 512];
    __shared__ float sl[512], fl[512];
    int tid = threadIdx.x;
    for (int i = tid; i < (31 * 512) / 8; i += 256)
        *(bf16x8*)&wl[i * 8] = *(const bf16x8*)&wT[i * 8];
    sl[tid] = scl[tid]; sl[tid + 256] = scl[tid + 256];
    fl[tid] = sft[tid]; fl[tid + 256] = sft[tid + 256];
    __syncthreads();

    int lane = tid & 63, sg = tid >> 6;
    int c = lane * 8;
    size_t bOff = (size_t)blockIdx.y * 1024 * 512;
    int sb = blockIdx.x * 16 + sg * 4;

    float acc[4][8] = {};
    for (int kk = 0; kk < 34; ++kk) {
        int sp = sb + kk - 15;
        if (sp < 0 || sp >= 1024) continue;
        bf16x8 xr = *(const bf16x8*)(X + bOff + (size_t)sp * 512 + c);
        float xv[8];
#pragma unroll
        for (int u = 0; u < 8; ++u) xv[u] = bits2f((unsigned short)xr[u]);
#pragma unroll
        for (int o = 0; o < 4; ++o) {
            int kw = kk - o;
            if (kw < 0 || kw > 30) continue;
            bf16x8 wv8 = *(const bf16x8*)&wl[kw * 512 + c];
#pragma unroll
            for (int u = 0; u < 8; ++u) acc[o][u] += xv[u] * bits2f((unsigned short)wv8[u]);
        }
    }
#pragma unroll
    for (int o = 0; o < 4; ++o) {
        __attribute__((aligned(16))) bf16 ov[8];
#pragma unroll
        for (int u = 0; u < 8; ++u) {
            float v = acc[o][u] * sl[c + u] + fl[c + u];
            v = v / (1.f + __expf(-v));
            ov[u] = f2b(v);
        }
        *(bf16x8*)(Out + bOff + (size_t)(sb + o) * 512 + c) = *(bf16x8*)ov;
    }
}

extern "C" void kernel_launch(void* const* d_in, const int* in_sizes, int n_in,
                              void* d_out, int out_size, void* d_ws, size_t ws_size,
                              hipStream_t stream) {
    const int B = 8, S = 1024, D = 512, F = 2048, H = 8;
    const int N = B * S;
    const size_t ND = (size_t)N * D;
    if (n_in < 37) return;

    int idx = 0;
    const void* x          = d_in[idx++];
    const void* ffn1_ln_g  = d_in[idx++];
    const void* ffn1_ln_b  = d_in[idx++];
    const void* ffn1_w1    = d_in[idx++];
    const void* ffn1_b1    = d_in[idx++];
    const void* ffn1_w2    = d_in[idx++];
    const void* ffn1_b2    = d_in[idx++];
    const void* mhsa_ln_g  = d_in[idx++];
    const void* mhsa_ln_b  = d_in[idx++];
    const void* wq         = d_in[idx++];
    const void* bq         = d_in[idx++];
    const void* wk         = d_in[idx++];
    const void* bk         = d_in[idx++];
    const void* wv         = d_in[idx++];
    const void* bv         = d_in[idx++];
    const void* wo         = d_in[idx++];
    const void* bo         = d_in[idx++];
    const void* conv_ln_g  = d_in[idx++];
    const void* conv_ln_b  = d_in[idx++];
    const void* pw1_w      = d_in[idx++];
    const void* pw1_b      = d_in[idx++];
    const void* dw_w       = d_in[idx++];
    const void* dw_b       = d_in[idx++];
    const void* bn_g       = d_in[idx++];
    const void* bn_b       = d_in[idx++];
    const void* bn_mean    = d_in[idx++];
    const void* bn_var     = d_in[idx++];
    const void* pw2_w      = d_in[idx++];
    const void* pw2_b      = d_in[idx++];
    const void* ffn2_ln_g  = d_in[idx++];
    const void* ffn2_ln_b  = d_in[idx++];
    const void* ffn2_w1    = d_in[idx++];
    const void* ffn2_b1    = d_in[idx++];
    const void* ffn2_w2    = d_in[idx++];
    const void* ffn2_b2    = d_in[idx++];
    const void* final_ln_g = d_in[idx++];
    const void* final_ln_b = d_in[idx++];

    const size_t MB = 1024 * 1024;
    char* wsb  = (char*)d_ws;
    int*  flag = (int*)wsb;
    float* res = (float*)(wsb + 1024);
    bf16*  wt  = (bf16*)(wsb + 1024 + ND * 4);
    char*  dwr = wsb + 1024 + ND * 4 + 4 * MB;
    bf16*  dwT  = (bf16*)dwr;
    float* dscl = (float*)(dwr + 32768);
    float* dsft = dscl + 512;
    char*  scr = dwr + 65536;
    size_t base = 1024 + ND * 4 + 4 * MB + 65536;
    size_t scrB = (ws_size > base) ? ws_size - base : 0;
    int ffnRows = (scrB >= 32 * MB) ? 8192 : ((scrB >= 8 * MB) ? 2048 : 1024);
    int bI      = (scrB >= 32 * MB) ? 8    : ((scrB >= 8 * MB) ? 2    : 1);
    int cI      = (scrB >= 32 * MB) ? 8    : ((scrB >= 8 * MB) ? 2    : 1);

    bf16* h = (bf16*)d_out;

    detect_kernel<<<1, 1, 0, stream>>>(ffn1_ln_g, flag);
    to_f32_kernel<<<(int)(ND / 8 / 256), 256, 0, stream>>>(x, res, (int)(ND / 8), flag);

    auto run_ffn = [&](const void* lg, const void* lb, const void* w1, const void* b1,
                       const void* w2, const void* b2) {
        bf16* w1t = wt;
        bf16* w2t = wt + (size_t)D * F;
        transpose_kernel<<<dim3(D / 32, F / 32), dim3(32, 8), 0, stream>>>(w1, w1t, D, F, flag);
        transpose_kernel<<<dim3(F / 32, D / 32), dim3(32, 8), 0, stream>>>(w2, w2t, F, D, flag);
        ln_kernel<<<N / 4, 256, 0, stream>>>(res, lg, lb, h, flag);
        bf16* mid = (bf16*)scr;
        for (int r0 = 0; r0 < N; r0 += ffnRows) {
            mgemm_kernel<1, 0><<<dim3(F / 128, ffnRows / 128), 256, 0, stream>>>(
                h + (size_t)r0 * D, w1t, b1, mid, nullptr, 0.f, D, F, flag);
            mgemm_kernel<0, 1><<<dim3(D / 128, ffnRows / 128), 256, 0, stream>>>(
                mid, w2t, b2, nullptr, res + (size_t)r0 * D, 0.5f, F, D, flag);
        }
    };

    // ---- FFN1 ----
    run_ffn(ffn1_ln_g, ffn1_ln_b, ffn1_w1, ffn1_b1, ffn1_w2, ffn1_b2);

    // ---- MHSA ----
    {
        bf16* qt = wt;
        bf16* kt = wt + (size_t)D * D;
        bf16* vt = wt + 2 * (size_t)D * D;
        bf16* ot = wt + 3 * (size_t)D * D;
        transpose_kernel<<<dim3(D / 32, D / 32), dim3(32, 8), 0, stream>>>(wq, qt, D, D, flag);
        transpose_kernel<<<dim3(D / 32, D / 32), dim3(32, 8), 0, stream>>>(wk, kt, D, D, flag);
        transpose_kernel<<<dim3(D / 32, D / 32), dim3(32, 8), 0, stream>>>(wv, vt, D, D, flag);
        transpose_kernel<<<dim3(D / 32, D / 32), dim3(32, 8), 0, stream>>>(wo, ot, D, D, flag);
        ln_kernel<<<N / 4, 256, 0, stream>>>(res, mhsa_ln_g, mhsa_ln_b, h, flag);
        for (int b = 0; b < B; b += bI) {
            int rows = bI * S;
            bf16* Q  = (bf16*)scr;
            bf16* Kb = Q  + (size_t)rows * D;
            bf16* V  = Kb + (size_t)rows * D;
            bf16* Vt = V  + (size_t)rows * D;
            const bf16* Ah = h + (size_t)b * S * D;
            mgemm_kernel<0, 0><<<dim3(D / 128, rows / 128), 256, 0, stream>>>(Ah, qt, bq, Q,  nullptr, 0.f, D, D, flag);
            mgemm_kernel<0, 0><<<dim3(D / 128, rows / 128), 256, 0, stream>>>(Ah, kt, bk, Kb, nullptr, 0.f, D, D, flag);
            mgemm_kernel<0, 0><<<dim3(D / 128, rows / 128), 256, 0, stream>>>(Ah, vt, bv, V,  nullptr, 0.f, D, D, flag);
            vtrans_kernel<<<dim3(S / 32, D / 32, bI), dim3(32, 8), 0, stream>>>(V, Vt);
            fattn_kernel<<<dim3(S / 64, H, bI), 256, 0, stream>>>(Q, Kb, Vt, Q);
            mgemm_kernel<0, 1><<<dim3(D / 128, rows / 128), 256, 0, stream>>>(
                Q, ot, bo, nullptr, res + (size_t)b * S * D, 1.0f, D, D, flag);
        }
    }

    // ---- Conv module ----
    {
        bf16* p1t = wt;
        bf16* p2t = wt + (size_t)D * 2 * D;
        transpose_kernel<<<dim3(D / 32, (2 * D) / 32), dim3(32, 8), 0, stream>>>(pw1_w, p1t, D, 2 * D, flag);
        transpose_kernel<<<dim3(D / 32, D / 32), dim3(32, 8), 0, stream>>>(pw2_w, p2t, D, D, flag);
        dwprep_kernel<<<2, 256, 0, stream>>>(dw_w, dw_b, bn_g, bn_b, bn_mean, bn_var, dwT, dscl, dsft, flag);
        ln_kernel<<<N / 4, 256, 0, stream>>>(res, conv_ln_g, conv_ln_b, h, flag);
        for (int b = 0; b < B; b += cI) {
            int rows = cI * S;
            bf16* u  = (bf16*)scr;
            bf16* hg = u + (size_t)rows * 2 * D;
            bf16* dw = hg + (size_t)rows * D;
            const bf16* Ah = h + (size_t)b * S * D;
            mgemm_kernel<0, 0><<<dim3((2 * D) / 128, rows / 128), 256, 0, stream>>>(
                Ah, p1t, pw1_b, u, nullptr, 0.f, D, 2 * D, flag);
            glu_kernel<<<(rows * D / 8) / 256, 256, 0, stream>>>(u, hg, rows * D / 8);
            dwconv_kernel<<<dim3(S / 16, cI), 256, 0, stream>>>(hg, dwT, dscl, dsft, dw);
            mgemm_kernel<0, 1><<<dim3(D / 128, rows / 128), 256, 0, stream>>>(
                dw, p2t, pw2_b, nullptr, res + (size_t)b * S * D, 1.0f, D, D, flag);
        }
    }

    // ---- FFN2 ----
    run_ffn(ffn2_ln_g, ffn2_ln_b, ffn2_w1, ffn2_b1, ffn2_w2, ffn2_b2);

    // ---- final LN -> d_out ----
    ln_out_kernel<<<N / 4, 256, 0, stream>>>(res, final_ln_g, final_ln_b, d_out, flag);
}